// Round 7
// baseline (3217.936 us; speedup 1.0000x reference)
//
#include <hip/hip_runtime.h>
#include <hip/hip_bf16.h>
#include <math.h>

// ---------------------------------------------------------------------------
// GNN: rep = attr @ W_inp^T + b
//      2x { x = (segsoftmax-weighted aggr of rep[src] by dst) + rep;
//           rep = LN(gelu(x @ W_a^T + b)) }
//      out = rep @ W_out^T + b_out
// segment_softmax(log a) == a / (ssum + amax*1e-16) -> per-node scalar.
// CSR by dst rebuilt per call via two-pass binning:
//   k_bin:  linear edge sweep -> per-(part,xcd) sub-bins (frontier writes are
//           XCD-local => full-line merges in L2, ~1x write amp) + deg atomics.
//   scan:   3-phase exclusive scan of deg -> row_ptr/cursor.
//   k_place: blocks pinned to xcd=blockIdx&7 handle parts {xcd, xcd+8};
//           reads that part's sub-bins, random-writes confined to the part's
//           1.6MB CSR region (read+write set < 4MiB L2 => no partial evicts).
// Node features packed bf16x2; dense layers bf16 MFMA with fused GELU+LN.
// ---------------------------------------------------------------------------

#define WAVE 64
#define NPARTS 16
#define CAP 14336         // sub-bin capacity (E/128 = 12500 avg, +16 sigma)
#define CHK 1792          // CAP/8 records per k_place block

typedef __attribute__((ext_vector_type(8))) short bf16x8;
typedef __attribute__((ext_vector_type(4))) float f32x4;
union ABu { uint4 u; bf16x8 v; };
union ABh { ushort h[8]; bf16x8 v; };

static __device__ __forceinline__ float bf2f(uint u16) {
    union { uint i; float f; } c;
    c.i = u16 << 16;
    return c.f;
}
static __device__ __forceinline__ uint f2bf(float f) {
    uint x = __float_as_uint(f);
    return (x + 0x7FFFu + ((x >> 16) & 1u)) >> 16;  // RNE
}

// ---- pass 1: bin edges by dst partition (XCD-local sub-bins) + deg count ----
__global__ __launch_bounds__(256) void k_bin(const int* __restrict__ src,
                                             const int* __restrict__ dst,
                                             const float* __restrict__ adv, int E,
                                             int PART, int* __restrict__ deg,
                                             int* __restrict__ subcnt,
                                             int4* __restrict__ bins) {
    int xcd = blockIdx.x & 7;
    for (int e = blockIdx.x * 256 + threadIdx.x; e < E; e += gridDim.x * 256) {
        int d = dst[e];
        int sb = (d / PART) * 8 + xcd;
        int p = atomicAdd(&subcnt[sb], 1);
        bins[(size_t)sb * CAP + p] =
            make_int4(src[e], __float_as_int(adv[e]), __float_as_int(adv[E + e]), d);
        atomicAdd(&deg[d], 1);
    }
}

// ---- 3-phase scan over deg[n] (n <= 256*256) ----
__global__ __launch_bounds__(256) void k_scan1(const int* __restrict__ deg, int n,
                                               int* __restrict__ excl,
                                               int* __restrict__ bsum) {
    __shared__ int sd[256];
    int t = threadIdx.x, i = blockIdx.x * 256 + t;
    int v = (i < n) ? deg[i] : 0;
    sd[t] = v;
    __syncthreads();
    for (int off = 1; off < 256; off <<= 1) {
        int u = (t >= off) ? sd[t - off] : 0;
        __syncthreads();
        sd[t] += u;
        __syncthreads();
    }
    if (i < n) excl[i] = sd[t] - v;
    if (t == 255) bsum[blockIdx.x] = sd[255];
}

__global__ __launch_bounds__(256) void k_scan2(int* __restrict__ bsum, int nb) {
    __shared__ int sd[256];
    int t = threadIdx.x;
    int v = (t < nb) ? bsum[t] : 0;
    sd[t] = v;
    __syncthreads();
    for (int off = 1; off < 256; off <<= 1) {
        int u = (t >= off) ? sd[t - off] : 0;
        __syncthreads();
        sd[t] += u;
        __syncthreads();
    }
    if (t < nb) bsum[t] = sd[t] - v;  // exclusive block offsets
}

__global__ __launch_bounds__(256) void k_scan3(const int* __restrict__ deg,
                                               const int* __restrict__ excl,
                                               const int* __restrict__ bsum, int n,
                                               int* __restrict__ row_ptr,
                                               int* __restrict__ cursor) {
    int i = blockIdx.x * 256 + threadIdx.x;
    if (i < n) {
        int rp = bsum[blockIdx.x] + excl[i];
        row_ptr[i] = rp;
        cursor[i] = rp;
        if (i == n - 1) row_ptr[n] = rp + deg[i];
    }
}

// ---- pass 3: place sub-bin records into CSR (XCD-confined regions) ----
__global__ __launch_bounds__(256) void k_place(const int4* __restrict__ bins,
                                               const int* __restrict__ subcnt,
                                               int* __restrict__ cursor,
                                               int4* __restrict__ csr) {
    int xcd = blockIdx.x & 7;
    int j = blockIdx.x >> 3;  // 0..63
    int s = j & 7;            // source sub-bin (writer xcd)
    int c = j >> 3;           // chunk 0..7
#pragma unroll
    for (int ph = 0; ph < NPARTS / 8; ++ph) {
        int part = xcd + ph * 8;
        int sb = part * 8 + s;
        int cnt = subcnt[sb];
        int hi = min(cnt, (c + 1) * CHK);
        for (int i = c * CHK + threadIdx.x; i < hi; i += 256) {
            int4 r = bins[(size_t)sb * CAP + i];
            int p = atomicAdd(&cursor[r.w], 1);
            csr[p] = r;
        }
    }
}

// ---- aggregation: one wave per node, single pass; rep packed bf16x2 ----
__global__ __launch_bounds__(512) void k_aggr(const uint* __restrict__ rep32,
                                              const int* __restrict__ row_ptr,
                                              const int4* __restrict__ csr, int aoff,
                                              uint* __restrict__ xout, int n) {
    int wave = threadIdx.x >> 6, lane = threadIdx.x & 63;
    int node = blockIdx.x * 8 + wave;
    if (node >= n) return;
    int s0 = row_ptr[node], s1 = row_ptr[node + 1];
    float accx = 0.f, accy = 0.f, ssum = 0.f, amax = 0.f;
    int s = s0;
    for (; s + 8 <= s1; s += 8) {
        int4 c0 = csr[s], c1 = csr[s + 1], c2 = csr[s + 2], c3 = csr[s + 3];
        int4 c4 = csr[s + 4], c5 = csr[s + 5], c6 = csr[s + 6], c7 = csr[s + 7];
        float a0 = __int_as_float(aoff == 1 ? c0.y : c0.z);
        float a1 = __int_as_float(aoff == 1 ? c1.y : c1.z);
        float a2 = __int_as_float(aoff == 1 ? c2.y : c2.z);
        float a3 = __int_as_float(aoff == 1 ? c3.y : c3.z);
        float a4 = __int_as_float(aoff == 1 ? c4.y : c4.z);
        float a5 = __int_as_float(aoff == 1 ? c5.y : c5.z);
        float a6 = __int_as_float(aoff == 1 ? c6.y : c6.z);
        float a7 = __int_as_float(aoff == 1 ? c7.y : c7.z);
        uint r0 = rep32[(size_t)c0.x * 64 + lane];
        uint r1 = rep32[(size_t)c1.x * 64 + lane];
        uint r2 = rep32[(size_t)c2.x * 64 + lane];
        uint r3 = rep32[(size_t)c3.x * 64 + lane];
        uint r4 = rep32[(size_t)c4.x * 64 + lane];
        uint r5 = rep32[(size_t)c5.x * 64 + lane];
        uint r6 = rep32[(size_t)c6.x * 64 + lane];
        uint r7 = rep32[(size_t)c7.x * 64 + lane];
        ssum += a0 + a1 + a2 + a3 + a4 + a5 + a6 + a7;
        amax = fmaxf(amax, fmaxf(fmaxf(fmaxf(a0, a1), fmaxf(a2, a3)),
                                 fmaxf(fmaxf(a4, a5), fmaxf(a6, a7))));
        accx = fmaf(a0, bf2f(r0 & 0xffffu), accx);
        accy = fmaf(a0, bf2f(r0 >> 16), accy);
        accx = fmaf(a1, bf2f(r1 & 0xffffu), accx);
        accy = fmaf(a1, bf2f(r1 >> 16), accy);
        accx = fmaf(a2, bf2f(r2 & 0xffffu), accx);
        accy = fmaf(a2, bf2f(r2 >> 16), accy);
        accx = fmaf(a3, bf2f(r3 & 0xffffu), accx);
        accy = fmaf(a3, bf2f(r3 >> 16), accy);
        accx = fmaf(a4, bf2f(r4 & 0xffffu), accx);
        accy = fmaf(a4, bf2f(r4 >> 16), accy);
        accx = fmaf(a5, bf2f(r5 & 0xffffu), accx);
        accy = fmaf(a5, bf2f(r5 >> 16), accy);
        accx = fmaf(a6, bf2f(r6 & 0xffffu), accx);
        accy = fmaf(a6, bf2f(r6 >> 16), accy);
        accx = fmaf(a7, bf2f(r7 & 0xffffu), accx);
        accy = fmaf(a7, bf2f(r7 >> 16), accy);
    }
    for (; s < s1; ++s) {
        int4 c = csr[s];
        float a = __int_as_float(aoff == 1 ? c.y : c.z);
        uint r = rep32[(size_t)c.x * 64 + lane];
        ssum += a;
        amax = fmaxf(amax, a);
        accx = fmaf(a, bf2f(r & 0xffffu), accx);
        accy = fmaf(a, bf2f(r >> 16), accy);
    }
    float inv = (s1 > s0) ? 1.f / (ssum + amax * 1e-16f) : 0.f;
    uint m = rep32[(size_t)node * 64 + lane];
    float ox = fmaf(accx, inv, bf2f(m & 0xffffu));
    float oy = fmaf(accy, inv, bf2f(m >> 16));
    xout[(size_t)node * 64 + lane] = f2bf(ox) | (f2bf(oy) << 16);
}

// ============================ dense MFMA kernels ============================
// 512 threads = 8 waves; wave handles 32 nodes (2 row-tiles of 16).
#define WROW 136  // shorts per LDS W row (128 + 8 pad -> 2-way banks = free)

// ---- MLP: rep(bf16) = LN(gelu(x(bf16) @ W^T + b)) ----
__global__ __launch_bounds__(512) void k_mlp(const uint* __restrict__ x32,
                                             const float* __restrict__ W,
                                             const float* __restrict__ b,
                                             const float* __restrict__ lw,
                                             const float* __restrict__ lb,
                                             uint* __restrict__ out32, int n) {
    __shared__ ushort Wbf[128 * WROW];
    uint* wd = (uint*)Wbf;
    for (int idx = threadIdx.x; idx < 128 * 64; idx += 512) {
        int row = idx >> 6, d = idx & 63;
        float2 w2 = *(const float2*)&W[row * 128 + d * 2];
        wd[row * (WROW / 2) + d] = f2bf(w2.x) | (f2bf(w2.y) << 16);
    }
    __syncthreads();
    int wv = threadIdx.x >> 6, l = threadIdx.x & 63;
    int c = l & 15, q = l >> 4;
    int base = blockIdx.x * 256 + wv * 32;
    int r0 = min(base + c, n - 1);
    int r1 = min(base + 16 + c, n - 1);

    f32x4 acc[2][8];
#pragma unroll
    for (int rt = 0; rt < 2; ++rt)
#pragma unroll
        for (int ct = 0; ct < 8; ++ct) acc[rt][ct] = (f32x4){0.f, 0.f, 0.f, 0.f};

#pragma unroll
    for (int kb = 0; kb < 4; ++kb) {
        ABu a0, a1;
        a0.u = *(const uint4*)&x32[(size_t)r0 * 64 + kb * 16 + q * 4];
        a1.u = *(const uint4*)&x32[(size_t)r1 * 64 + kb * 16 + q * 4];
#pragma unroll
        for (int ct = 0; ct < 8; ++ct) {
            bf16x8 bf = *(const bf16x8*)&Wbf[(ct * 16 + c) * WROW + kb * 32 + q * 8];
            acc[0][ct] = __builtin_amdgcn_mfma_f32_16x16x32_bf16(a0.v, bf, acc[0][ct], 0, 0, 0);
            acc[1][ct] = __builtin_amdgcn_mfma_f32_16x16x32_bf16(a1.v, bf, acc[1][ct], 0, 0, 0);
        }
    }

    float bias[8], lwv[8], lbv[8];
#pragma unroll
    for (int ct = 0; ct < 8; ++ct) {
        bias[ct] = b[ct * 16 + c];
        lwv[ct] = lw[ct * 16 + c];
        lbv[ct] = lb[ct * 16 + c];
    }

#pragma unroll
    for (int rt = 0; rt < 2; ++rt) {
#pragma unroll
        for (int ct = 0; ct < 8; ++ct)
#pragma unroll
            for (int i = 0; i < 4; ++i) {
                float h = acc[rt][ct][i] + bias[ct];
                acc[rt][ct][i] = 0.5f * h * (1.f + erff(h * 0.70710678118654752f));
            }
        float mu[4], rstd[4];
#pragma unroll
        for (int i = 0; i < 4; ++i) {
            float s = 0.f;
#pragma unroll
            for (int ct = 0; ct < 8; ++ct) s += acc[rt][ct][i];
            s += __shfl_xor(s, 1);
            s += __shfl_xor(s, 2);
            s += __shfl_xor(s, 4);
            s += __shfl_xor(s, 8);
            mu[i] = s * (1.f / 128.f);
        }
#pragma unroll
        for (int i = 0; i < 4; ++i) {
            float v = 0.f;
#pragma unroll
            for (int ct = 0; ct < 8; ++ct) {
                float d = acc[rt][ct][i] - mu[i];
                v += d * d;
            }
            v += __shfl_xor(v, 1);
            v += __shfl_xor(v, 2);
            v += __shfl_xor(v, 4);
            v += __shfl_xor(v, 8);
            rstd[i] = rsqrtf(v * (1.f / 128.f) + 1e-5f);
        }
#pragma unroll
        for (int ct = 0; ct < 8; ++ct)
#pragma unroll
            for (int i = 0; i < 4; ++i) {
                float o = (acc[rt][ct][i] - mu[i]) * rstd[i] * lwv[ct] + lbv[ct];
                float p = __shfl_xor(o, 1);
                uint dw = (c & 1) ? (f2bf(p) | (f2bf(o) << 16))
                                  : (f2bf(o) | (f2bf(p) << 16));
                int R = base + rt * 16 + q * 4 + i;
                if (R < n && (c & 1) == 0)
                    out32[(size_t)R * 64 + ct * 8 + (c >> 1)] = dw;
            }
    }
}

// ---- input projection: rep(bf16) = attr(f32) @ W^T + b ----
__global__ __launch_bounds__(512) void k_input(const float* __restrict__ attr,
                                               const float* __restrict__ W,
                                               const float* __restrict__ b,
                                               uint* __restrict__ out32, int n) {
    __shared__ ushort Wbf[128 * WROW];
    uint* wd = (uint*)Wbf;
    for (int idx = threadIdx.x; idx < 128 * 64; idx += 512) {
        int row = idx >> 6, d = idx & 63;
        float2 w2 = *(const float2*)&W[row * 128 + d * 2];
        wd[row * (WROW / 2) + d] = f2bf(w2.x) | (f2bf(w2.y) << 16);
    }
    __syncthreads();
    int wv = threadIdx.x >> 6, l = threadIdx.x & 63;
    int c = l & 15, q = l >> 4;
    int base = blockIdx.x * 256 + wv * 32;
    int r0 = min(base + c, n - 1);
    int r1 = min(base + 16 + c, n - 1);

    f32x4 acc[2][8];
#pragma unroll
    for (int rt = 0; rt < 2; ++rt)
#pragma unroll
        for (int ct = 0; ct < 8; ++ct) acc[rt][ct] = (f32x4){0.f, 0.f, 0.f, 0.f};

#pragma unroll
    for (int kb = 0; kb < 4; ++kb) {
        ABh a0, a1;
        float4 f0 = *(const float4*)&attr[(size_t)r0 * 128 + kb * 32 + q * 8];
        float4 f1 = *(const float4*)&attr[(size_t)r0 * 128 + kb * 32 + q * 8 + 4];
        a0.h[0] = f2bf(f0.x); a0.h[1] = f2bf(f0.y); a0.h[2] = f2bf(f0.z); a0.h[3] = f2bf(f0.w);
        a0.h[4] = f2bf(f1.x); a0.h[5] = f2bf(f1.y); a0.h[6] = f2bf(f1.z); a0.h[7] = f2bf(f1.w);
        float4 g0 = *(const float4*)&attr[(size_t)r1 * 128 + kb * 32 + q * 8];
        float4 g1 = *(const float4*)&attr[(size_t)r1 * 128 + kb * 32 + q * 8 + 4];
        a1.h[0] = f2bf(g0.x); a1.h[1] = f2bf(g0.y); a1.h[2] = f2bf(g0.z); a1.h[3] = f2bf(g0.w);
        a1.h[4] = f2bf(g1.x); a1.h[5] = f2bf(g1.y); a1.h[6] = f2bf(g1.z); a1.h[7] = f2bf(g1.w);
#pragma unroll
        for (int ct = 0; ct < 8; ++ct) {
            bf16x8 bf = *(const bf16x8*)&Wbf[(ct * 16 + c) * WROW + kb * 32 + q * 8];
            acc[0][ct] = __builtin_amdgcn_mfma_f32_16x16x32_bf16(a0.v, bf, acc[0][ct], 0, 0, 0);
            acc[1][ct] = __builtin_amdgcn_mfma_f32_16x16x32_bf16(a1.v, bf, acc[1][ct], 0, 0, 0);
        }
    }
    float bias[8];
#pragma unroll
    for (int ct = 0; ct < 8; ++ct) bias[ct] = b[ct * 16 + c];
#pragma unroll
    for (int rt = 0; rt < 2; ++rt)
#pragma unroll
        for (int ct = 0; ct < 8; ++ct)
#pragma unroll
            for (int i = 0; i < 4; ++i) {
                float o = acc[rt][ct][i] + bias[ct];
                float p = __shfl_xor(o, 1);
                uint dw = (c & 1) ? (f2bf(p) | (f2bf(o) << 16))
                                  : (f2bf(o) | (f2bf(p) << 16));
                int R = base + rt * 16 + q * 4 + i;
                if (R < n && (c & 1) == 0)
                    out32[(size_t)R * 64 + ct * 8 + (c >> 1)] = dw;
            }
}

// ---- output projection: out(f32) = rep(bf16) @ W_out^T + b_out (64 outs) ----
__global__ __launch_bounds__(512) void k_out(const uint* __restrict__ rep32,
                                             const float* __restrict__ W,
                                             const float* __restrict__ b,
                                             float* __restrict__ out, int n) {
    __shared__ ushort Wbf[64 * WROW];
    uint* wd = (uint*)Wbf;
    for (int idx = threadIdx.x; idx < 64 * 64; idx += 512) {
        int row = idx >> 6, d = idx & 63;
        float2 w2 = *(const float2*)&W[row * 128 + d * 2];
        wd[row * (WROW / 2) + d] = f2bf(w2.x) | (f2bf(w2.y) << 16);
    }
    __syncthreads();
    int wv = threadIdx.x >> 6, l = threadIdx.x & 63;
    int c = l & 15, q = l >> 4;
    int base = blockIdx.x * 256 + wv * 32;
    int r0 = min(base + c, n - 1);
    int r1 = min(base + 16 + c, n - 1);

    f32x4 acc[2][4];
#pragma unroll
    for (int rt = 0; rt < 2; ++rt)
#pragma unroll
        for (int ct = 0; ct < 4; ++ct) acc[rt][ct] = (f32x4){0.f, 0.f, 0.f, 0.f};

#pragma unroll
    for (int kb = 0; kb < 4; ++kb) {
        ABu a0, a1;
        a0.u = *(const uint4*)&rep32[(size_t)r0 * 64 + kb * 16 + q * 4];
        a1.u = *(const uint4*)&rep32[(size_t)r1 * 64 + kb * 16 + q * 4];
#pragma unroll
        for (int ct = 0; ct < 4; ++ct) {
            bf16x8 bf = *(const bf16x8*)&Wbf[(ct * 16 + c) * WROW + kb * 32 + q * 8];
            acc[0][ct] = __builtin_amdgcn_mfma_f32_16x16x32_bf16(a0.v, bf, acc[0][ct], 0, 0, 0);
            acc[1][ct] = __builtin_amdgcn_mfma_f32_16x16x32_bf16(a1.v, bf, acc[1][ct], 0, 0, 0);
        }
    }
    float bias[4];
#pragma unroll
    for (int ct = 0; ct < 4; ++ct) bias[ct] = b[ct * 16 + c];
#pragma unroll
    for (int rt = 0; rt < 2; ++rt)
#pragma unroll
        for (int ct = 0; ct < 4; ++ct)
#pragma unroll
            for (int i = 0; i < 4; ++i) {
                int R = base + rt * 16 + q * 4 + i;
                if (R < n) out[(size_t)R * 64 + ct * 16 + c] = acc[rt][ct][i] + bias[ct];
            }
}

extern "C" void kernel_launch(void* const* d_in, const int* in_sizes, int n_in,
                              void* d_out, int out_size, void* d_ws, size_t ws_size,
                              hipStream_t stream) {
    const float* node_attr = (const float*)d_in[0];
    const int* ei = (const int*)d_in[1];
    // d_in[2] = batch_idx (unused)
    const float* adv = (const float*)d_in[3];
    const float* W_inp = (const float*)d_in[4];
    const float* b_inp = (const float*)d_in[5];
    const float* W_a = (const float*)d_in[6];
    const float* b_a = (const float*)d_in[7];
    const float* ln_w = (const float*)d_in[8];
    const float* ln_b = (const float*)d_in[9];
    const float* W_out = (const float*)d_in[10];
    const float* b_out = (const float*)d_in[11];

    const int n = in_sizes[0] / 128;
    const int E = in_sizes[1] / 2;

    // workspace: csr (E int4) | bins (128*CAP int4, later overlaid by A,B) | misc
    int4* csr = (int4*)d_ws;
    int4* bins = csr + E;
    uint* A = (uint*)bins;               // A,B overlay bins (bins dead by then)
    uint* B = A + (size_t)n * 64;
    int* misc = (int*)(bins + (size_t)128 * CAP);
    int* deg = misc;                     // n
    int* subcnt = deg + n;               // 128
    int* cursor = subcnt + 128;          // n
    int* excl = cursor + n;              // n
    int* row_ptr = excl + n;             // n+1
    int* bsum = row_ptr + n + 1;         // 256

    const int* src = ei;
    const int* dst = ei + E;
    const int PART = (n + NPARTS - 1) / NPARTS;

    hipMemsetAsync(deg, 0, (size_t)(n + 128) * sizeof(int), stream);

    int nbs = (n + 255) / 256;
    k_bin<<<1024, 256, 0, stream>>>(src, dst, adv, E, PART, deg, subcnt, bins);
    k_scan1<<<nbs, 256, 0, stream>>>(deg, n, excl, bsum);
    k_scan2<<<1, 256, 0, stream>>>(bsum, nbs);
    k_scan3<<<nbs, 256, 0, stream>>>(deg, excl, bsum, n, row_ptr, cursor);
    k_place<<<512, 256, 0, stream>>>(bins, subcnt, cursor, csr);

    int nbd = (n + 255) / 256;  // dense kernels: 256 nodes/block
    int nb8 = (n + 7) / 8;
    k_input<<<nbd, 512, 0, stream>>>(node_attr, W_inp, b_inp, A, n);

    // layer 0: B = aggr(A); A = mlp(B)
    k_aggr<<<nb8, 512, 0, stream>>>(A, row_ptr, csr, 1, B, n);
    k_mlp<<<nbd, 512, 0, stream>>>(B, W_a, b_a, ln_w, ln_b, A, n);
    // layer 1: B = aggr(A); A = mlp(B)
    k_aggr<<<nb8, 512, 0, stream>>>(A, row_ptr, csr, 2, B, n);
    k_mlp<<<nbd, 512, 0, stream>>>(B, W_a + 128 * 128, b_a + 128,
                                   ln_w + 128, ln_b + 128, A, n);

    k_out<<<nbd, 512, 0, stream>>>(A, W_out, b_out, (float*)d_out, n);
}

// Round 8
// 391.854 us; speedup vs baseline: 8.2121x; 8.2121x over previous
//
#include <hip/hip_runtime.h>
#include <hip/hip_bf16.h>
#include <math.h>

// ---------------------------------------------------------------------------
// GNN: rep = attr @ W_inp^T + b
//      2x { x = (segsoftmax-weighted aggr of rep[src] by dst) + rep;
//           rep = LN(gelu(x @ W_a^T + b)) }
//      out = rep @ W_out^T + b_out
// segment_softmax(log a) == a / (ssum + amax*1e-16) -> per-node scalar.
// CSR by dst rebuilt per call:
//   k_count: rank[e] = atomicAdd(&deg[dst[e]],1)  (per-node cursors: 50K
//            addresses, ~32 hits each -> low contention; NEVER use few hot
//            counters: 128-address append cursors cost 230ns/op serialized)
//   scan:    3-phase exclusive scan of deg -> row_ptr
//   k_scatter: ATOMIC-FREE placement csr[row_ptr[d]+rank[e]]; XCD-partitioned
//            (16 dst parts, xcd=blockIdx&7 does parts {x,x+8}) so each XCD's
//            active random-write window ~1.6MB < 4MiB L2 for line merging.
// Node features packed bf16x2; dense layers bf16 MFMA with fused GELU+LN.
// ---------------------------------------------------------------------------

#define WAVE 64
#define NPARTS 16
#define SCHUNK 4096

typedef __attribute__((ext_vector_type(8))) short bf16x8;
typedef __attribute__((ext_vector_type(4))) float f32x4;
union ABu { uint4 u; bf16x8 v; };
union ABh { ushort h[8]; bf16x8 v; };

static __device__ __forceinline__ float bf2f(uint u16) {
    union { uint i; float f; } c;
    c.i = u16 << 16;
    return c.f;
}
static __device__ __forceinline__ uint f2bf(float f) {
    uint x = __float_as_uint(f);
    return (x + 0x7FFFu + ((x >> 16) & 1u)) >> 16;  // RNE
}

// ---- count + rank: per-node cursor atomics ----
__global__ void k_count(const int* __restrict__ dst, int E,
                        int* __restrict__ deg, int* __restrict__ rank) {
    int e = blockIdx.x * blockDim.x + threadIdx.x;
    if (e < E) rank[e] = atomicAdd(&deg[dst[e]], 1);
}

// ---- 3-phase scan over deg[n] (n <= 256*256) ----
__global__ __launch_bounds__(256) void k_scan1(const int* __restrict__ deg, int n,
                                               int* __restrict__ excl,
                                               int* __restrict__ bsum) {
    __shared__ int sd[256];
    int t = threadIdx.x, i = blockIdx.x * 256 + t;
    int v = (i < n) ? deg[i] : 0;
    sd[t] = v;
    __syncthreads();
    for (int off = 1; off < 256; off <<= 1) {
        int u = (t >= off) ? sd[t - off] : 0;
        __syncthreads();
        sd[t] += u;
        __syncthreads();
    }
    if (i < n) excl[i] = sd[t] - v;
    if (t == 255) bsum[blockIdx.x] = sd[255];
}

__global__ __launch_bounds__(256) void k_scan2(int* __restrict__ bsum, int nb) {
    __shared__ int sd[256];
    int t = threadIdx.x;
    int v = (t < nb) ? bsum[t] : 0;
    sd[t] = v;
    __syncthreads();
    for (int off = 1; off < 256; off <<= 1) {
        int u = (t >= off) ? sd[t - off] : 0;
        __syncthreads();
        sd[t] += u;
        __syncthreads();
    }
    if (t < nb) bsum[t] = sd[t] - v;  // exclusive block offsets
}

__global__ __launch_bounds__(256) void k_scan3(const int* __restrict__ deg,
                                               const int* __restrict__ excl,
                                               const int* __restrict__ bsum, int n,
                                               int* __restrict__ row_ptr) {
    int i = blockIdx.x * 256 + threadIdx.x;
    if (i < n) {
        int rp = bsum[blockIdx.x] + excl[i];
        row_ptr[i] = rp;
        if (i == n - 1) row_ptr[n] = rp + deg[i];
    }
}

// ---- scatter: atomic-free, XCD-partitioned writes ----
__global__ __launch_bounds__(256) void k_scatter(const int* __restrict__ src,
                                                 const int* __restrict__ dst,
                                                 const float* __restrict__ adv,
                                                 const int* __restrict__ rank,
                                                 const int* __restrict__ row_ptr,
                                                 int E, int n,
                                                 int4* __restrict__ csr) {
    int xcd = blockIdx.x & 7;
    int chunk = blockIdx.x >> 3;
    int PART = (n + NPARTS - 1) / NPARTS;
    int base = chunk * SCHUNK + threadIdx.x;
    for (int ph = 0; ph < NPARTS / 8; ++ph) {
        int part = xcd + ph * 8;
        int lo = part * PART, hi = min(lo + PART, n);
#pragma unroll
        for (int i = 0; i < SCHUNK / 256; ++i) {
            int e = base + i * 256;
            if (e < E) {
                int d = dst[e];
                if (d >= lo && d < hi) {
                    int p = row_ptr[d] + rank[e];
                    csr[p] = make_int4(src[e], __float_as_int(adv[e]),
                                       __float_as_int(adv[E + e]), 0);
                }
            }
        }
    }
}

// ---- aggregation: one wave per node, single pass; rep packed bf16x2 ----
__global__ __launch_bounds__(512) void k_aggr(const uint* __restrict__ rep32,
                                              const int* __restrict__ row_ptr,
                                              const int4* __restrict__ csr, int aoff,
                                              uint* __restrict__ xout, int n) {
    int wave = threadIdx.x >> 6, lane = threadIdx.x & 63;
    int node = blockIdx.x * 8 + wave;
    if (node >= n) return;
    int s0 = row_ptr[node], s1 = row_ptr[node + 1];
    float accx = 0.f, accy = 0.f, ssum = 0.f, amax = 0.f;
    int s = s0;
    for (; s + 8 <= s1; s += 8) {
        int4 c0 = csr[s], c1 = csr[s + 1], c2 = csr[s + 2], c3 = csr[s + 3];
        int4 c4 = csr[s + 4], c5 = csr[s + 5], c6 = csr[s + 6], c7 = csr[s + 7];
        float a0 = __int_as_float(aoff == 1 ? c0.y : c0.z);
        float a1 = __int_as_float(aoff == 1 ? c1.y : c1.z);
        float a2 = __int_as_float(aoff == 1 ? c2.y : c2.z);
        float a3 = __int_as_float(aoff == 1 ? c3.y : c3.z);
        float a4 = __int_as_float(aoff == 1 ? c4.y : c4.z);
        float a5 = __int_as_float(aoff == 1 ? c5.y : c5.z);
        float a6 = __int_as_float(aoff == 1 ? c6.y : c6.z);
        float a7 = __int_as_float(aoff == 1 ? c7.y : c7.z);
        uint r0 = rep32[(size_t)c0.x * 64 + lane];
        uint r1 = rep32[(size_t)c1.x * 64 + lane];
        uint r2 = rep32[(size_t)c2.x * 64 + lane];
        uint r3 = rep32[(size_t)c3.x * 64 + lane];
        uint r4 = rep32[(size_t)c4.x * 64 + lane];
        uint r5 = rep32[(size_t)c5.x * 64 + lane];
        uint r6 = rep32[(size_t)c6.x * 64 + lane];
        uint r7 = rep32[(size_t)c7.x * 64 + lane];
        ssum += a0 + a1 + a2 + a3 + a4 + a5 + a6 + a7;
        amax = fmaxf(amax, fmaxf(fmaxf(fmaxf(a0, a1), fmaxf(a2, a3)),
                                 fmaxf(fmaxf(a4, a5), fmaxf(a6, a7))));
        accx = fmaf(a0, bf2f(r0 & 0xffffu), accx);
        accy = fmaf(a0, bf2f(r0 >> 16), accy);
        accx = fmaf(a1, bf2f(r1 & 0xffffu), accx);
        accy = fmaf(a1, bf2f(r1 >> 16), accy);
        accx = fmaf(a2, bf2f(r2 & 0xffffu), accx);
        accy = fmaf(a2, bf2f(r2 >> 16), accy);
        accx = fmaf(a3, bf2f(r3 & 0xffffu), accx);
        accy = fmaf(a3, bf2f(r3 >> 16), accy);
        accx = fmaf(a4, bf2f(r4 & 0xffffu), accx);
        accy = fmaf(a4, bf2f(r4 >> 16), accy);
        accx = fmaf(a5, bf2f(r5 & 0xffffu), accx);
        accy = fmaf(a5, bf2f(r5 >> 16), accy);
        accx = fmaf(a6, bf2f(r6 & 0xffffu), accx);
        accy = fmaf(a6, bf2f(r6 >> 16), accy);
        accx = fmaf(a7, bf2f(r7 & 0xffffu), accx);
        accy = fmaf(a7, bf2f(r7 >> 16), accy);
    }
    for (; s < s1; ++s) {
        int4 c = csr[s];
        float a = __int_as_float(aoff == 1 ? c.y : c.z);
        uint r = rep32[(size_t)c.x * 64 + lane];
        ssum += a;
        amax = fmaxf(amax, a);
        accx = fmaf(a, bf2f(r & 0xffffu), accx);
        accy = fmaf(a, bf2f(r >> 16), accy);
    }
    float inv = (s1 > s0) ? 1.f / (ssum + amax * 1e-16f) : 0.f;
    uint m = rep32[(size_t)node * 64 + lane];
    float ox = fmaf(accx, inv, bf2f(m & 0xffffu));
    float oy = fmaf(accy, inv, bf2f(m >> 16));
    xout[(size_t)node * 64 + lane] = f2bf(ox) | (f2bf(oy) << 16);
}

// ============================ dense MFMA kernels ============================
// 512 threads = 8 waves; wave handles 32 nodes (2 row-tiles of 16).
#define WROW 136  // shorts per LDS W row (128 + 8 pad -> 2-way banks = free)

// ---- MLP: rep(bf16) = LN(gelu(x(bf16) @ W^T + b)) ----
__global__ __launch_bounds__(512) void k_mlp(const uint* __restrict__ x32,
                                             const float* __restrict__ W,
                                             const float* __restrict__ b,
                                             const float* __restrict__ lw,
                                             const float* __restrict__ lb,
                                             uint* __restrict__ out32, int n) {
    __shared__ ushort Wbf[128 * WROW];
    uint* wd = (uint*)Wbf;
    for (int idx = threadIdx.x; idx < 128 * 64; idx += 512) {
        int row = idx >> 6, d = idx & 63;
        float2 w2 = *(const float2*)&W[row * 128 + d * 2];
        wd[row * (WROW / 2) + d] = f2bf(w2.x) | (f2bf(w2.y) << 16);
    }
    __syncthreads();
    int wv = threadIdx.x >> 6, l = threadIdx.x & 63;
    int c = l & 15, q = l >> 4;
    int base = blockIdx.x * 256 + wv * 32;
    int r0 = min(base + c, n - 1);
    int r1 = min(base + 16 + c, n - 1);

    f32x4 acc[2][8];
#pragma unroll
    for (int rt = 0; rt < 2; ++rt)
#pragma unroll
        for (int ct = 0; ct < 8; ++ct) acc[rt][ct] = (f32x4){0.f, 0.f, 0.f, 0.f};

#pragma unroll
    for (int kb = 0; kb < 4; ++kb) {
        ABu a0, a1;
        a0.u = *(const uint4*)&x32[(size_t)r0 * 64 + kb * 16 + q * 4];
        a1.u = *(const uint4*)&x32[(size_t)r1 * 64 + kb * 16 + q * 4];
#pragma unroll
        for (int ct = 0; ct < 8; ++ct) {
            bf16x8 bf = *(const bf16x8*)&Wbf[(ct * 16 + c) * WROW + kb * 32 + q * 8];
            acc[0][ct] = __builtin_amdgcn_mfma_f32_16x16x32_bf16(a0.v, bf, acc[0][ct], 0, 0, 0);
            acc[1][ct] = __builtin_amdgcn_mfma_f32_16x16x32_bf16(a1.v, bf, acc[1][ct], 0, 0, 0);
        }
    }

    float bias[8], lwv[8], lbv[8];
#pragma unroll
    for (int ct = 0; ct < 8; ++ct) {
        bias[ct] = b[ct * 16 + c];
        lwv[ct] = lw[ct * 16 + c];
        lbv[ct] = lb[ct * 16 + c];
    }

#pragma unroll
    for (int rt = 0; rt < 2; ++rt) {
#pragma unroll
        for (int ct = 0; ct < 8; ++ct)
#pragma unroll
            for (int i = 0; i < 4; ++i) {
                float h = acc[rt][ct][i] + bias[ct];
                acc[rt][ct][i] = 0.5f * h * (1.f + erff(h * 0.70710678118654752f));
            }
        float mu[4], rstd[4];
#pragma unroll
        for (int i = 0; i < 4; ++i) {
            float s = 0.f;
#pragma unroll
            for (int ct = 0; ct < 8; ++ct) s += acc[rt][ct][i];
            s += __shfl_xor(s, 1);
            s += __shfl_xor(s, 2);
            s += __shfl_xor(s, 4);
            s += __shfl_xor(s, 8);
            mu[i] = s * (1.f / 128.f);
        }
#pragma unroll
        for (int i = 0; i < 4; ++i) {
            float v = 0.f;
#pragma unroll
            for (int ct = 0; ct < 8; ++ct) {
                float d = acc[rt][ct][i] - mu[i];
                v += d * d;
            }
            v += __shfl_xor(v, 1);
            v += __shfl_xor(v, 2);
            v += __shfl_xor(v, 4);
            v += __shfl_xor(v, 8);
            rstd[i] = rsqrtf(v * (1.f / 128.f) + 1e-5f);
        }
#pragma unroll
        for (int ct = 0; ct < 8; ++ct)
#pragma unroll
            for (int i = 0; i < 4; ++i) {
                float o = (acc[rt][ct][i] - mu[i]) * rstd[i] * lwv[ct] + lbv[ct];
                float p = __shfl_xor(o, 1);
                uint dw = (c & 1) ? (f2bf(p) | (f2bf(o) << 16))
                                  : (f2bf(o) | (f2bf(p) << 16));
                int R = base + rt * 16 + q * 4 + i;
                if (R < n && (c & 1) == 0)
                    out32[(size_t)R * 64 + ct * 8 + (c >> 1)] = dw;
            }
    }
}

// ---- input projection: rep(bf16) = attr(f32) @ W^T + b ----
__global__ __launch_bounds__(512) void k_input(const float* __restrict__ attr,
                                               const float* __restrict__ W,
                                               const float* __restrict__ b,
                                               uint* __restrict__ out32, int n) {
    __shared__ ushort Wbf[128 * WROW];
    uint* wd = (uint*)Wbf;
    for (int idx = threadIdx.x; idx < 128 * 64; idx += 512) {
        int row = idx >> 6, d = idx & 63;
        float2 w2 = *(const float2*)&W[row * 128 + d * 2];
        wd[row * (WROW / 2) + d] = f2bf(w2.x) | (f2bf(w2.y) << 16);
    }
    __syncthreads();
    int wv = threadIdx.x >> 6, l = threadIdx.x & 63;
    int c = l & 15, q = l >> 4;
    int base = blockIdx.x * 256 + wv * 32;
    int r0 = min(base + c, n - 1);
    int r1 = min(base + 16 + c, n - 1);

    f32x4 acc[2][8];
#pragma unroll
    for (int rt = 0; rt < 2; ++rt)
#pragma unroll
        for (int ct = 0; ct < 8; ++ct) acc[rt][ct] = (f32x4){0.f, 0.f, 0.f, 0.f};

#pragma unroll
    for (int kb = 0; kb < 4; ++kb) {
        ABh a0, a1;
        float4 f0 = *(const float4*)&attr[(size_t)r0 * 128 + kb * 32 + q * 8];
        float4 f1 = *(const float4*)&attr[(size_t)r0 * 128 + kb * 32 + q * 8 + 4];
        a0.h[0] = f2bf(f0.x); a0.h[1] = f2bf(f0.y); a0.h[2] = f2bf(f0.z); a0.h[3] = f2bf(f0.w);
        a0.h[4] = f2bf(f1.x); a0.h[5] = f2bf(f1.y); a0.h[6] = f2bf(f1.z); a0.h[7] = f2bf(f1.w);
        float4 g0 = *(const float4*)&attr[(size_t)r1 * 128 + kb * 32 + q * 8];
        float4 g1 = *(const float4*)&attr[(size_t)r1 * 128 + kb * 32 + q * 8 + 4];
        a1.h[0] = f2bf(g0.x); a1.h[1] = f2bf(g0.y); a1.h[2] = f2bf(g0.z); a1.h[3] = f2bf(g0.w);
        a1.h[4] = f2bf(g1.x); a1.h[5] = f2bf(g1.y); a1.h[6] = f2bf(g1.z); a1.h[7] = f2bf(g1.w);
#pragma unroll
        for (int ct = 0; ct < 8; ++ct) {
            bf16x8 bf = *(const bf16x8*)&Wbf[(ct * 16 + c) * WROW + kb * 32 + q * 8];
            acc[0][ct] = __builtin_amdgcn_mfma_f32_16x16x32_bf16(a0.v, bf, acc[0][ct], 0, 0, 0);
            acc[1][ct] = __builtin_amdgcn_mfma_f32_16x16x32_bf16(a1.v, bf, acc[1][ct], 0, 0, 0);
        }
    }
    float bias[8];
#pragma unroll
    for (int ct = 0; ct < 8; ++ct) bias[ct] = b[ct * 16 + c];
#pragma unroll
    for (int rt = 0; rt < 2; ++rt)
#pragma unroll
        for (int ct = 0; ct < 8; ++ct)
#pragma unroll
            for (int i = 0; i < 4; ++i) {
                float o = acc[rt][ct][i] + bias[ct];
                float p = __shfl_xor(o, 1);
                uint dw = (c & 1) ? (f2bf(p) | (f2bf(o) << 16))
                                  : (f2bf(o) | (f2bf(p) << 16));
                int R = base + rt * 16 + q * 4 + i;
                if (R < n && (c & 1) == 0)
                    out32[(size_t)R * 64 + ct * 8 + (c >> 1)] = dw;
            }
}

// ---- output projection: out(f32) = rep(bf16) @ W_out^T + b_out (64 outs) ----
__global__ __launch_bounds__(512) void k_out(const uint* __restrict__ rep32,
                                             const float* __restrict__ W,
                                             const float* __restrict__ b,
                                             float* __restrict__ out, int n) {
    __shared__ ushort Wbf[64 * WROW];
    uint* wd = (uint*)Wbf;
    for (int idx = threadIdx.x; idx < 64 * 64; idx += 512) {
        int row = idx >> 6, d = idx & 63;
        float2 w2 = *(const float2*)&W[row * 128 + d * 2];
        wd[row * (WROW / 2) + d] = f2bf(w2.x) | (f2bf(w2.y) << 16);
    }
    __syncthreads();
    int wv = threadIdx.x >> 6, l = threadIdx.x & 63;
    int c = l & 15, q = l >> 4;
    int base = blockIdx.x * 256 + wv * 32;
    int r0 = min(base + c, n - 1);
    int r1 = min(base + 16 + c, n - 1);

    f32x4 acc[2][4];
#pragma unroll
    for (int rt = 0; rt < 2; ++rt)
#pragma unroll
        for (int ct = 0; ct < 4; ++ct) acc[rt][ct] = (f32x4){0.f, 0.f, 0.f, 0.f};

#pragma unroll
    for (int kb = 0; kb < 4; ++kb) {
        ABu a0, a1;
        a0.u = *(const uint4*)&rep32[(size_t)r0 * 64 + kb * 16 + q * 4];
        a1.u = *(const uint4*)&rep32[(size_t)r1 * 64 + kb * 16 + q * 4];
#pragma unroll
        for (int ct = 0; ct < 4; ++ct) {
            bf16x8 bf = *(const bf16x8*)&Wbf[(ct * 16 + c) * WROW + kb * 32 + q * 8];
            acc[0][ct] = __builtin_amdgcn_mfma_f32_16x16x32_bf16(a0.v, bf, acc[0][ct], 0, 0, 0);
            acc[1][ct] = __builtin_amdgcn_mfma_f32_16x16x32_bf16(a1.v, bf, acc[1][ct], 0, 0, 0);
        }
    }
    float bias[4];
#pragma unroll
    for (int ct = 0; ct < 4; ++ct) bias[ct] = b[ct * 16 + c];
#pragma unroll
    for (int rt = 0; rt < 2; ++rt)
#pragma unroll
        for (int ct = 0; ct < 4; ++ct)
#pragma unroll
            for (int i = 0; i < 4; ++i) {
                int R = base + rt * 16 + q * 4 + i;
                if (R < n) out[(size_t)R * 64 + ct * 16 + c] = acc[rt][ct][i] + bias[ct];
            }
}

extern "C" void kernel_launch(void* const* d_in, const int* in_sizes, int n_in,
                              void* d_out, int out_size, void* d_ws, size_t ws_size,
                              hipStream_t stream) {
    const float* node_attr = (const float*)d_in[0];
    const int* ei = (const int*)d_in[1];
    // d_in[2] = batch_idx (unused)
    const float* adv = (const float*)d_in[3];
    const float* W_inp = (const float*)d_in[4];
    const float* b_inp = (const float*)d_in[5];
    const float* W_a = (const float*)d_in[6];
    const float* b_a = (const float*)d_in[7];
    const float* ln_w = (const float*)d_in[8];
    const float* ln_b = (const float*)d_in[9];
    const float* W_out = (const float*)d_in[10];
    const float* b_out = (const float*)d_in[11];

    const int n = in_sizes[0] / 128;
    const int E = in_sizes[1] / 2;

    // workspace: csr (E int4) | A,B (bf16x2, n*64 dwords) | rank (E) | misc
    int4* csr = (int4*)d_ws;
    uint* A = (uint*)(csr + E);
    uint* B = A + (size_t)n * 64;
    int* rank = (int*)(B + (size_t)n * 64);  // E
    int* deg = rank + E;                     // n
    int* excl = deg + n;                     // n
    int* row_ptr = excl + n;                 // n+1
    int* bsum = row_ptr + n + 1;             // 256

    const int* src = ei;
    const int* dst = ei + E;

    hipMemsetAsync(deg, 0, (size_t)n * sizeof(int), stream);

    int eb = (E + 255) / 256;
    int nbs = (n + 255) / 256;  // n <= 65536 supported by k_scan2
    k_count<<<eb, 256, 0, stream>>>(dst, E, deg, rank);
    k_scan1<<<nbs, 256, 0, stream>>>(deg, n, excl, bsum);
    k_scan2<<<1, 256, 0, stream>>>(bsum, nbs);
    k_scan3<<<nbs, 256, 0, stream>>>(deg, excl, bsum, n, row_ptr);
    int sb = 8 * ((E + SCHUNK - 1) / SCHUNK);
    k_scatter<<<sb, 256, 0, stream>>>(src, dst, adv, rank, row_ptr, E, n, csr);

    int nbd = (n + 255) / 256;  // dense kernels: 256 nodes/block
    int nb8 = (n + 7) / 8;
    k_input<<<nbd, 512, 0, stream>>>(node_attr, W_inp, b_inp, A, n);

    // layer 0: B = aggr(A); A = mlp(B)
    k_aggr<<<nb8, 512, 0, stream>>>(A, row_ptr, csr, 1, B, n);
    k_mlp<<<nbd, 512, 0, stream>>>(B, W_a, b_a, ln_w, ln_b, A, n);
    // layer 1: B = aggr(A); A = mlp(B)
    k_aggr<<<nb8, 512, 0, stream>>>(A, row_ptr, csr, 2, B, n);
    k_mlp<<<nbd, 512, 0, stream>>>(B, W_a + 128 * 128, b_a + 128,
                                   ln_w + 128, ln_b + 128, A, n);

    k_out<<<nbd, 512, 0, stream>>>(A, W_out, b_out, (float*)d_out, n);
}

// Round 9
// 343.823 us; speedup vs baseline: 9.3593x; 1.1397x over previous
//
#include <hip/hip_runtime.h>
#include <hip/hip_bf16.h>
#include <math.h>

// ---------------------------------------------------------------------------
// GNN: rep = attr @ W_inp^T + b
//      2x { x = (segsoftmax-weighted aggr of rep[src] by dst) + rep;
//           rep = LN(gelu(x @ W_a^T + b)) }
//      out = rep @ W_out^T + b_out
// segment_softmax(log a) == a / (ssum + amax*1e-16) -> per-node scalar.
// CSR build (per call):
//   k_count: rank[e] = atomicAdd(&deg[dst[e]],1)   (per-node cursors, low
//            contention; NEVER few hot counters -> 230ns/op serialization)
//   scan:    3-phase exclusive scan of deg -> row_ptr
//   k_bin:   one pass over edges; LDS histogram/scan/reorder by 32 dst-parts;
//            records (src,a0,a1,pos) flushed coalesced to tmp; pos =
//            row_ptr[dst]+rank precomputed.  (reads everything exactly once)
//   k_place: XCD-pinned blocks read partition segments sequentially, write
//            csr[pos] confined to ~800KB window per XCD -> L2 line merging.
// Node features packed bf16x2; dense layers bf16 MFMA with fused GELU+LN.
// ---------------------------------------------------------------------------

#define WAVE 64
#define NPARTS 32
#define CHUNKE 4096
#define CB 64   // chunk-parallel blocks per xcd-lane in k_place

typedef __attribute__((ext_vector_type(8))) short bf16x8;
typedef __attribute__((ext_vector_type(4))) float f32x4;
union ABu { uint4 u; bf16x8 v; };
union ABh { ushort h[8]; bf16x8 v; };

static __device__ __forceinline__ float bf2f(uint u16) {
    union { uint i; float f; } c;
    c.i = u16 << 16;
    return c.f;
}
static __device__ __forceinline__ uint f2bf(float f) {
    uint x = __float_as_uint(f);
    return (x + 0x7FFFu + ((x >> 16) & 1u)) >> 16;  // RNE
}

// ---- count + rank: per-node cursor atomics ----
__global__ void k_count(const int* __restrict__ dst, int E,
                        int* __restrict__ deg, int* __restrict__ rank) {
    int e = blockIdx.x * blockDim.x + threadIdx.x;
    if (e < E) rank[e] = atomicAdd(&deg[dst[e]], 1);
}

// ---- 3-phase scan over deg[n] (n <= 256*256) ----
__global__ __launch_bounds__(256) void k_scan1(const int* __restrict__ deg, int n,
                                               int* __restrict__ excl,
                                               int* __restrict__ bsum) {
    __shared__ int sd[256];
    int t = threadIdx.x, i = blockIdx.x * 256 + t;
    int v = (i < n) ? deg[i] : 0;
    sd[t] = v;
    __syncthreads();
    for (int off = 1; off < 256; off <<= 1) {
        int u = (t >= off) ? sd[t - off] : 0;
        __syncthreads();
        sd[t] += u;
        __syncthreads();
    }
    if (i < n) excl[i] = sd[t] - v;
    if (t == 255) bsum[blockIdx.x] = sd[255];
}

__global__ __launch_bounds__(256) void k_scan2(int* __restrict__ bsum, int nb) {
    __shared__ int sd[256];
    int t = threadIdx.x;
    int v = (t < nb) ? bsum[t] : 0;
    sd[t] = v;
    __syncthreads();
    for (int off = 1; off < 256; off <<= 1) {
        int u = (t >= off) ? sd[t - off] : 0;
        __syncthreads();
        sd[t] += u;
        __syncthreads();
    }
    if (t < nb) bsum[t] = sd[t] - v;  // exclusive block offsets
}

__global__ __launch_bounds__(256) void k_scan3(const int* __restrict__ deg,
                                               const int* __restrict__ excl,
                                               const int* __restrict__ bsum, int n,
                                               int* __restrict__ row_ptr) {
    int i = blockIdx.x * 256 + threadIdx.x;
    if (i < n) {
        int rp = bsum[blockIdx.x] + excl[i];
        row_ptr[i] = rp;
        if (i == n - 1) row_ptr[n] = rp + deg[i];
    }
}

// ---- pass 1: chunk-local LDS sort by dst partition; records carry final pos ----
__global__ __launch_bounds__(256) void k_bin(const int* __restrict__ src,
                                             const int* __restrict__ dst,
                                             const float* __restrict__ adv,
                                             const int* __restrict__ rank,
                                             const int* __restrict__ row_ptr,
                                             int E, int PART,
                                             int4* __restrict__ tmp,
                                             int* __restrict__ bstart,
                                             int* __restrict__ bcnt) {
    __shared__ int hist[NPARTS], cur[NPARTS], base_[NPARTS];
    __shared__ int4 buf[CHUNKE];
    int c = blockIdx.x;
    int e0 = c * CHUNKE;
    int cnt = min(CHUNKE, E - e0);
    int dreg[CHUNKE / 256];
    int preg[CHUNKE / 256];
    if (threadIdx.x < NPARTS) hist[threadIdx.x] = 0;
    __syncthreads();
#pragma unroll
    for (int i = 0; i < CHUNKE / 256; ++i) {
        int idx = threadIdx.x + i * 256;
        if (idx < cnt) {
            int d = dst[e0 + idx];
            int pt = d / PART;
            dreg[i] = d;
            preg[i] = pt;
            atomicAdd(&hist[pt], 1);
        }
    }
    __syncthreads();
    if (threadIdx.x == 0) {
        int run = 0;
        for (int p = 0; p < NPARTS; ++p) {
            base_[p] = run;
            cur[p] = run;
            run += hist[p];
        }
    }
    __syncthreads();
#pragma unroll
    for (int i = 0; i < CHUNKE / 256; ++i) {
        int idx = threadIdx.x + i * 256;
        if (idx < cnt) {
            int e = e0 + idx;
            int slot = atomicAdd(&cur[preg[i]], 1);
            int pos = row_ptr[dreg[i]] + rank[e];
            buf[slot] = make_int4(src[e], __float_as_int(adv[e]),
                                  __float_as_int(adv[E + e]), pos);
        }
    }
    __syncthreads();
    for (int i = threadIdx.x; i < cnt; i += 256) tmp[(size_t)e0 + i] = buf[i];
    if (threadIdx.x < NPARTS) {
        bstart[c * NPARTS + threadIdx.x] = e0 + base_[threadIdx.x];
        bcnt[c * NPARTS + threadIdx.x] = hist[threadIdx.x];
    }
}

// ---- pass 2: XCD-pinned placement into partition-confined CSR windows ----
__global__ __launch_bounds__(256) void k_place(const int4* __restrict__ tmp,
                                               const int* __restrict__ bstart,
                                               const int* __restrict__ bcnt,
                                               int nchunk, int4* __restrict__ csr) {
    int xcd = blockIdx.x & 7;
    int j = blockIdx.x >> 3;  // 0..CB-1
    for (int ph = 0; ph < NPARTS / 8; ++ph) {
        int part = xcd + 8 * ph;
        for (int c = j; c < nchunk; c += CB) {
            int s = bstart[c * NPARTS + part];
            int cnt = bcnt[c * NPARTS + part];
            for (int i = threadIdx.x; i < cnt; i += 256) {
                int4 r = tmp[(size_t)s + i];
                csr[r.w] = r;
            }
        }
    }
}

// ---- aggregation: one wave per node, single pass; rep packed bf16x2 ----
__global__ __launch_bounds__(512) void k_aggr(const uint* __restrict__ rep32,
                                              const int* __restrict__ row_ptr,
                                              const int4* __restrict__ csr, int aoff,
                                              uint* __restrict__ xout, int n) {
    int wave = threadIdx.x >> 6, lane = threadIdx.x & 63;
    int node = blockIdx.x * 8 + wave;
    if (node >= n) return;
    int s0 = row_ptr[node], s1 = row_ptr[node + 1];
    float accx = 0.f, accy = 0.f, ssum = 0.f, amax = 0.f;
    int s = s0;
    for (; s + 8 <= s1; s += 8) {
        int4 c0 = csr[s], c1 = csr[s + 1], c2 = csr[s + 2], c3 = csr[s + 3];
        int4 c4 = csr[s + 4], c5 = csr[s + 5], c6 = csr[s + 6], c7 = csr[s + 7];
        float a0 = __int_as_float(aoff == 1 ? c0.y : c0.z);
        float a1 = __int_as_float(aoff == 1 ? c1.y : c1.z);
        float a2 = __int_as_float(aoff == 1 ? c2.y : c2.z);
        float a3 = __int_as_float(aoff == 1 ? c3.y : c3.z);
        float a4 = __int_as_float(aoff == 1 ? c4.y : c4.z);
        float a5 = __int_as_float(aoff == 1 ? c5.y : c5.z);
        float a6 = __int_as_float(aoff == 1 ? c6.y : c6.z);
        float a7 = __int_as_float(aoff == 1 ? c7.y : c7.z);
        uint r0 = rep32[(size_t)c0.x * 64 + lane];
        uint r1 = rep32[(size_t)c1.x * 64 + lane];
        uint r2 = rep32[(size_t)c2.x * 64 + lane];
        uint r3 = rep32[(size_t)c3.x * 64 + lane];
        uint r4 = rep32[(size_t)c4.x * 64 + lane];
        uint r5 = rep32[(size_t)c5.x * 64 + lane];
        uint r6 = rep32[(size_t)c6.x * 64 + lane];
        uint r7 = rep32[(size_t)c7.x * 64 + lane];
        ssum += a0 + a1 + a2 + a3 + a4 + a5 + a6 + a7;
        amax = fmaxf(amax, fmaxf(fmaxf(fmaxf(a0, a1), fmaxf(a2, a3)),
                                 fmaxf(fmaxf(a4, a5), fmaxf(a6, a7))));
        accx = fmaf(a0, bf2f(r0 & 0xffffu), accx);
        accy = fmaf(a0, bf2f(r0 >> 16), accy);
        accx = fmaf(a1, bf2f(r1 & 0xffffu), accx);
        accy = fmaf(a1, bf2f(r1 >> 16), accy);
        accx = fmaf(a2, bf2f(r2 & 0xffffu), accx);
        accy = fmaf(a2, bf2f(r2 >> 16), accy);
        accx = fmaf(a3, bf2f(r3 & 0xffffu), accx);
        accy = fmaf(a3, bf2f(r3 >> 16), accy);
        accx = fmaf(a4, bf2f(r4 & 0xffffu), accx);
        accy = fmaf(a4, bf2f(r4 >> 16), accy);
        accx = fmaf(a5, bf2f(r5 & 0xffffu), accx);
        accy = fmaf(a5, bf2f(r5 >> 16), accy);
        accx = fmaf(a6, bf2f(r6 & 0xffffu), accx);
        accy = fmaf(a6, bf2f(r6 >> 16), accy);
        accx = fmaf(a7, bf2f(r7 & 0xffffu), accx);
        accy = fmaf(a7, bf2f(r7 >> 16), accy);
    }
    for (; s < s1; ++s) {
        int4 c = csr[s];
        float a = __int_as_float(aoff == 1 ? c.y : c.z);
        uint r = rep32[(size_t)c.x * 64 + lane];
        ssum += a;
        amax = fmaxf(amax, a);
        accx = fmaf(a, bf2f(r & 0xffffu), accx);
        accy = fmaf(a, bf2f(r >> 16), accy);
    }
    float inv = (s1 > s0) ? 1.f / (ssum + amax * 1e-16f) : 0.f;
    uint m = rep32[(size_t)node * 64 + lane];
    float ox = fmaf(accx, inv, bf2f(m & 0xffffu));
    float oy = fmaf(accy, inv, bf2f(m >> 16));
    xout[(size_t)node * 64 + lane] = f2bf(ox) | (f2bf(oy) << 16);
}

// ============================ dense MFMA kernels ============================
// 512 threads = 8 waves; wave handles 32 nodes (2 row-tiles of 16).
#define WROW 136  // shorts per LDS W row (128 + 8 pad -> 2-way banks = free)

// ---- MLP: rep(bf16) = LN(gelu(x(bf16) @ W^T + b)) ----
__global__ __launch_bounds__(512) void k_mlp(const uint* __restrict__ x32,
                                             const float* __restrict__ W,
                                             const float* __restrict__ b,
                                             const float* __restrict__ lw,
                                             const float* __restrict__ lb,
                                             uint* __restrict__ out32, int n) {
    __shared__ ushort Wbf[128 * WROW];
    uint* wd = (uint*)Wbf;
    for (int idx = threadIdx.x; idx < 128 * 64; idx += 512) {
        int row = idx >> 6, d = idx & 63;
        float2 w2 = *(const float2*)&W[row * 128 + d * 2];
        wd[row * (WROW / 2) + d] = f2bf(w2.x) | (f2bf(w2.y) << 16);
    }
    __syncthreads();
    int wv = threadIdx.x >> 6, l = threadIdx.x & 63;
    int c = l & 15, q = l >> 4;
    int base = blockIdx.x * 256 + wv * 32;
    int r0 = min(base + c, n - 1);
    int r1 = min(base + 16 + c, n - 1);

    f32x4 acc[2][8];
#pragma unroll
    for (int rt = 0; rt < 2; ++rt)
#pragma unroll
        for (int ct = 0; ct < 8; ++ct) acc[rt][ct] = (f32x4){0.f, 0.f, 0.f, 0.f};

#pragma unroll
    for (int kb = 0; kb < 4; ++kb) {
        ABu a0, a1;
        a0.u = *(const uint4*)&x32[(size_t)r0 * 64 + kb * 16 + q * 4];
        a1.u = *(const uint4*)&x32[(size_t)r1 * 64 + kb * 16 + q * 4];
#pragma unroll
        for (int ct = 0; ct < 8; ++ct) {
            bf16x8 bf = *(const bf16x8*)&Wbf[(ct * 16 + c) * WROW + kb * 32 + q * 8];
            acc[0][ct] = __builtin_amdgcn_mfma_f32_16x16x32_bf16(a0.v, bf, acc[0][ct], 0, 0, 0);
            acc[1][ct] = __builtin_amdgcn_mfma_f32_16x16x32_bf16(a1.v, bf, acc[1][ct], 0, 0, 0);
        }
    }

    float bias[8], lwv[8], lbv[8];
#pragma unroll
    for (int ct = 0; ct < 8; ++ct) {
        bias[ct] = b[ct * 16 + c];
        lwv[ct] = lw[ct * 16 + c];
        lbv[ct] = lb[ct * 16 + c];
    }

#pragma unroll
    for (int rt = 0; rt < 2; ++rt) {
#pragma unroll
        for (int ct = 0; ct < 8; ++ct)
#pragma unroll
            for (int i = 0; i < 4; ++i) {
                float h = acc[rt][ct][i] + bias[ct];
                acc[rt][ct][i] = 0.5f * h * (1.f + erff(h * 0.70710678118654752f));
            }
        float mu[4], rstd[4];
#pragma unroll
        for (int i = 0; i < 4; ++i) {
            float s = 0.f;
#pragma unroll
            for (int ct = 0; ct < 8; ++ct) s += acc[rt][ct][i];
            s += __shfl_xor(s, 1);
            s += __shfl_xor(s, 2);
            s += __shfl_xor(s, 4);
            s += __shfl_xor(s, 8);
            mu[i] = s * (1.f / 128.f);
        }
#pragma unroll
        for (int i = 0; i < 4; ++i) {
            float v = 0.f;
#pragma unroll
            for (int ct = 0; ct < 8; ++ct) {
                float d = acc[rt][ct][i] - mu[i];
                v += d * d;
            }
            v += __shfl_xor(v, 1);
            v += __shfl_xor(v, 2);
            v += __shfl_xor(v, 4);
            v += __shfl_xor(v, 8);
            rstd[i] = rsqrtf(v * (1.f / 128.f) + 1e-5f);
        }
#pragma unroll
        for (int ct = 0; ct < 8; ++ct)
#pragma unroll
            for (int i = 0; i < 4; ++i) {
                float o = (acc[rt][ct][i] - mu[i]) * rstd[i] * lwv[ct] + lbv[ct];
                float p = __shfl_xor(o, 1);
                uint dw = (c & 1) ? (f2bf(p) | (f2bf(o) << 16))
                                  : (f2bf(o) | (f2bf(p) << 16));
                int R = base + rt * 16 + q * 4 + i;
                if (R < n && (c & 1) == 0)
                    out32[(size_t)R * 64 + ct * 8 + (c >> 1)] = dw;
            }
    }
}

// ---- input projection: rep(bf16) = attr(f32) @ W^T + b ----
__global__ __launch_bounds__(512) void k_input(const float* __restrict__ attr,
                                               const float* __restrict__ W,
                                               const float* __restrict__ b,
                                               uint* __restrict__ out32, int n) {
    __shared__ ushort Wbf[128 * WROW];
    uint* wd = (uint*)Wbf;
    for (int idx = threadIdx.x; idx < 128 * 64; idx += 512) {
        int row = idx >> 6, d = idx & 63;
        float2 w2 = *(const float2*)&W[row * 128 + d * 2];
        wd[row * (WROW / 2) + d] = f2bf(w2.x) | (f2bf(w2.y) << 16);
    }
    __syncthreads();
    int wv = threadIdx.x >> 6, l = threadIdx.x & 63;
    int c = l & 15, q = l >> 4;
    int base = blockIdx.x * 256 + wv * 32;
    int r0 = min(base + c, n - 1);
    int r1 = min(base + 16 + c, n - 1);

    f32x4 acc[2][8];
#pragma unroll
    for (int rt = 0; rt < 2; ++rt)
#pragma unroll
        for (int ct = 0; ct < 8; ++ct) acc[rt][ct] = (f32x4){0.f, 0.f, 0.f, 0.f};

#pragma unroll
    for (int kb = 0; kb < 4; ++kb) {
        ABh a0, a1;
        float4 f0 = *(const float4*)&attr[(size_t)r0 * 128 + kb * 32 + q * 8];
        float4 f1 = *(const float4*)&attr[(size_t)r0 * 128 + kb * 32 + q * 8 + 4];
        a0.h[0] = f2bf(f0.x); a0.h[1] = f2bf(f0.y); a0.h[2] = f2bf(f0.z); a0.h[3] = f2bf(f0.w);
        a0.h[4] = f2bf(f1.x); a0.h[5] = f2bf(f1.y); a0.h[6] = f2bf(f1.z); a0.h[7] = f2bf(f1.w);
        float4 g0 = *(const float4*)&attr[(size_t)r1 * 128 + kb * 32 + q * 8];
        float4 g1 = *(const float4*)&attr[(size_t)r1 * 128 + kb * 32 + q * 8 + 4];
        a1.h[0] = f2bf(g0.x); a1.h[1] = f2bf(g0.y); a1.h[2] = f2bf(g0.z); a1.h[3] = f2bf(g0.w);
        a1.h[4] = f2bf(g1.x); a1.h[5] = f2bf(g1.y); a1.h[6] = f2bf(g1.z); a1.h[7] = f2bf(g1.w);
#pragma unroll
        for (int ct = 0; ct < 8; ++ct) {
            bf16x8 bf = *(const bf16x8*)&Wbf[(ct * 16 + c) * WROW + kb * 32 + q * 8];
            acc[0][ct] = __builtin_amdgcn_mfma_f32_16x16x32_bf16(a0.v, bf, acc[0][ct], 0, 0, 0);
            acc[1][ct] = __builtin_amdgcn_mfma_f32_16x16x32_bf16(a1.v, bf, acc[1][ct], 0, 0, 0);
        }
    }
    float bias[8];
#pragma unroll
    for (int ct = 0; ct < 8; ++ct) bias[ct] = b[ct * 16 + c];
#pragma unroll
    for (int rt = 0; rt < 2; ++rt)
#pragma unroll
        for (int ct = 0; ct < 8; ++ct)
#pragma unroll
            for (int i = 0; i < 4; ++i) {
                float o = acc[rt][ct][i] + bias[ct];
                float p = __shfl_xor(o, 1);
                uint dw = (c & 1) ? (f2bf(p) | (f2bf(o) << 16))
                                  : (f2bf(o) | (f2bf(p) << 16));
                int R = base + rt * 16 + q * 4 + i;
                if (R < n && (c & 1) == 0)
                    out32[(size_t)R * 64 + ct * 8 + (c >> 1)] = dw;
            }
}

// ---- output projection: out(f32) = rep(bf16) @ W_out^T + b_out (64 outs) ----
__global__ __launch_bounds__(512) void k_out(const uint* __restrict__ rep32,
                                             const float* __restrict__ W,
                                             const float* __restrict__ b,
                                             float* __restrict__ out, int n) {
    __shared__ ushort Wbf[64 * WROW];
    uint* wd = (uint*)Wbf;
    for (int idx = threadIdx.x; idx < 64 * 64; idx += 512) {
        int row = idx >> 6, d = idx & 63;
        float2 w2 = *(const float2*)&W[row * 128 + d * 2];
        wd[row * (WROW / 2) + d] = f2bf(w2.x) | (f2bf(w2.y) << 16);
    }
    __syncthreads();
    int wv = threadIdx.x >> 6, l = threadIdx.x & 63;
    int c = l & 15, q = l >> 4;
    int base = blockIdx.x * 256 + wv * 32;
    int r0 = min(base + c, n - 1);
    int r1 = min(base + 16 + c, n - 1);

    f32x4 acc[2][4];
#pragma unroll
    for (int rt = 0; rt < 2; ++rt)
#pragma unroll
        for (int ct = 0; ct < 4; ++ct) acc[rt][ct] = (f32x4){0.f, 0.f, 0.f, 0.f};

#pragma unroll
    for (int kb = 0; kb < 4; ++kb) {
        ABu a0, a1;
        a0.u = *(const uint4*)&rep32[(size_t)r0 * 64 + kb * 16 + q * 4];
        a1.u = *(const uint4*)&rep32[(size_t)r1 * 64 + kb * 16 + q * 4];
#pragma unroll
        for (int ct = 0; ct < 4; ++ct) {
            bf16x8 bf = *(const bf16x8*)&Wbf[(ct * 16 + c) * WROW + kb * 32 + q * 8];
            acc[0][ct] = __builtin_amdgcn_mfma_f32_16x16x32_bf16(a0.v, bf, acc[0][ct], 0, 0, 0);
            acc[1][ct] = __builtin_amdgcn_mfma_f32_16x16x32_bf16(a1.v, bf, acc[1][ct], 0, 0, 0);
        }
    }
    float bias[4];
#pragma unroll
    for (int ct = 0; ct < 4; ++ct) bias[ct] = b[ct * 16 + c];
#pragma unroll
    for (int rt = 0; rt < 2; ++rt)
#pragma unroll
        for (int ct = 0; ct < 4; ++ct)
#pragma unroll
            for (int i = 0; i < 4; ++i) {
                int R = base + rt * 16 + q * 4 + i;
                if (R < n) out[(size_t)R * 64 + ct * 16 + c] = acc[rt][ct][i] + bias[ct];
            }
}

extern "C" void kernel_launch(void* const* d_in, const int* in_sizes, int n_in,
                              void* d_out, int out_size, void* d_ws, size_t ws_size,
                              hipStream_t stream) {
    const float* node_attr = (const float*)d_in[0];
    const int* ei = (const int*)d_in[1];
    // d_in[2] = batch_idx (unused)
    const float* adv = (const float*)d_in[3];
    const float* W_inp = (const float*)d_in[4];
    const float* b_inp = (const float*)d_in[5];
    const float* W_a = (const float*)d_in[6];
    const float* b_a = (const float*)d_in[7];
    const float* ln_w = (const float*)d_in[8];
    const float* ln_b = (const float*)d_in[9];
    const float* W_out = (const float*)d_in[10];
    const float* b_out = (const float*)d_in[11];

    const int n = in_sizes[0] / 128;
    const int E = in_sizes[1] / 2;
    const int nchunk = (E + CHUNKE - 1) / CHUNKE;
    const int PART = (n + NPARTS - 1) / NPARTS;

    // workspace: csr (E int4) | tmp (E int4, overlaid by A,B after build) |
    //            rank (E) | deg n | excl n | row_ptr n+1 | bsum 256 |
    //            bstart nchunk*NPARTS | bcnt nchunk*NPARTS
    int4* csr = (int4*)d_ws;
    int4* tmp = csr + E;
    uint* A = (uint*)tmp;      // overlays tmp (dead after k_place)
    uint* B = A + (size_t)n * 64;
    int* rank = (int*)(tmp + E);
    int* deg = rank + E;
    int* excl = deg + n;
    int* row_ptr = excl + n;           // n+1
    int* bsum = row_ptr + n + 1;       // 256
    int* bstart = bsum + 256;          // nchunk*NPARTS
    int* bcnt = bstart + (size_t)nchunk * NPARTS;

    const int* src = ei;
    const int* dst = ei + E;

    hipMemsetAsync(deg, 0, (size_t)n * sizeof(int), stream);

    int eb = (E + 255) / 256;
    int nbs = (n + 255) / 256;  // n <= 65536 supported by k_scan2
    k_count<<<eb, 256, 0, stream>>>(dst, E, deg, rank);
    k_scan1<<<nbs, 256, 0, stream>>>(deg, n, excl, bsum);
    k_scan2<<<1, 256, 0, stream>>>(bsum, nbs);
    k_scan3<<<nbs, 256, 0, stream>>>(deg, excl, bsum, n, row_ptr);
    k_bin<<<nchunk, 256, 0, stream>>>(src, dst, adv, rank, row_ptr, E, PART,
                                      tmp, bstart, bcnt);
    k_place<<<8 * CB, 256, 0, stream>>>(tmp, bstart, bcnt, nchunk, csr);

    int nbd = (n + 255) / 256;  // dense kernels: 256 nodes/block
    int nb8 = (n + 7) / 8;
    k_input<<<nbd, 512, 0, stream>>>(node_attr, W_inp, b_inp, A, n);

    // layer 0: B = aggr(A); A = mlp(B)
    k_aggr<<<nb8, 512, 0, stream>>>(A, row_ptr, csr, 1, B, n);
    k_mlp<<<nbd, 512, 0, stream>>>(B, W_a, b_a, ln_w, ln_b, A, n);
    // layer 1: B = aggr(A); A = mlp(B)
    k_aggr<<<nb8, 512, 0, stream>>>(A, row_ptr, csr, 2, B, n);
    k_mlp<<<nbd, 512, 0, stream>>>(B, W_a + 128 * 128, b_a + 128,
                                   ln_w + 128, ln_b + 128, A, n);

    k_out<<<nbd, 512, 0, stream>>>(A, W_out, b_out, (float*)d_out, n);
}

// Round 10
// 319.164 us; speedup vs baseline: 10.0824x; 1.0773x over previous
//
#include <hip/hip_runtime.h>
#include <hip/hip_bf16.h>
#include <math.h>

// ---------------------------------------------------------------------------
// GNN: rep = attr @ W_inp^T + b
//      2x { x = (segsoftmax-weighted aggr of rep[src] by dst) + rep;
//           rep = LN(gelu(x @ W_a^T + b)) }
//      out = rep @ W_out^T + b_out
// segment_softmax(log a) == a / (ssum + amax*1e-16) -> per-node scalar.
// CSR build (per call), all edge streams read exactly once:
//   k_bin:   single pass; rank = atomicAdd(&deg[dst]) inline (per-node
//            cursors only -- NEVER few hot counters, 230ns/op serialized);
//            LDS histogram/scan/reorder by 32 dst-parts; records
//            (src,a0,a1,dst|rank<<16) flushed coalesced to tmp.
//   scan:    scan1 (per-256 blocks) + scan3b (redundant LDS scan of bsums).
//   k_place: XCD-pinned blocks read partition segments sequentially, compute
//            pos=row_ptr[dst]+rank, write csr0[pos]=(src,a0), csr1[pos]=
//            (src,a1) confined to ~0.8MB windows per XCD -> L2 line merging.
// k_aggr reads 8B records/edge/layer. Node features packed bf16x2; dense
// layers bf16 MFMA (16x16x32) with fused bias/GELU/LN epilogues.
// ---------------------------------------------------------------------------

#define WAVE 64
#define NPARTS 32
#define CHUNKE 4096
#define CB 64   // chunk-parallel blocks per xcd-lane in k_place

typedef __attribute__((ext_vector_type(8))) short bf16x8;
typedef __attribute__((ext_vector_type(4))) float f32x4;
union ABu { uint4 u; bf16x8 v; };
union ABh { ushort h[8]; bf16x8 v; };

static __device__ __forceinline__ float bf2f(uint u16) {
    union { uint i; float f; } c;
    c.i = u16 << 16;
    return c.f;
}
static __device__ __forceinline__ uint f2bf(float f) {
    uint x = __float_as_uint(f);
    return (x + 0x7FFFu + ((x >> 16) & 1u)) >> 16;  // RNE
}

// ---- pass 1: chunk-local LDS sort by dst partition; rank computed inline ----
__global__ __launch_bounds__(256) void k_bin(const int* __restrict__ src,
                                             const int* __restrict__ dst,
                                             const float* __restrict__ adv,
                                             int E, int PART,
                                             int* __restrict__ deg,
                                             int4* __restrict__ tmp,
                                             int* __restrict__ bstart,
                                             int* __restrict__ bcnt) {
    __shared__ int hist[NPARTS], cur[NPARTS], base_[NPARTS];
    __shared__ int4 buf[CHUNKE];
    int c = blockIdx.x;
    int e0 = c * CHUNKE;
    int cnt = min(CHUNKE, E - e0);
    int dreg[CHUNKE / 256];
    int preg[CHUNKE / 256];
    if (threadIdx.x < NPARTS) hist[threadIdx.x] = 0;
    __syncthreads();
#pragma unroll
    for (int i = 0; i < CHUNKE / 256; ++i) {
        int idx = threadIdx.x + i * 256;
        if (idx < cnt) {
            int d = dst[e0 + idx];
            int pt = d / PART;
            dreg[i] = d;
            preg[i] = pt;
            atomicAdd(&hist[pt], 1);
        }
    }
    __syncthreads();
    if (threadIdx.x == 0) {
        int run = 0;
        for (int p = 0; p < NPARTS; ++p) {
            base_[p] = run;
            cur[p] = run;
            run += hist[p];
        }
    }
    __syncthreads();
#pragma unroll
    for (int i = 0; i < CHUNKE / 256; ++i) {
        int idx = threadIdx.x + i * 256;
        if (idx < cnt) {
            int e = e0 + idx;
            int slot = atomicAdd(&cur[preg[i]], 1);
            int rk = atomicAdd(&deg[dreg[i]], 1);  // rank within row (any order)
            buf[slot] = make_int4(src[e], __float_as_int(adv[e]),
                                  __float_as_int(adv[E + e]),
                                  dreg[i] | (rk << 16));
        }
    }
    __syncthreads();
    for (int i = threadIdx.x; i < cnt; i += 256) tmp[(size_t)e0 + i] = buf[i];
    if (threadIdx.x < NPARTS) {
        bstart[c * NPARTS + threadIdx.x] = e0 + base_[threadIdx.x];
        bcnt[c * NPARTS + threadIdx.x] = hist[threadIdx.x];
    }
}

// ---- scan: per-256-chunk scan, then per-block redundant scan of bsums ----
__global__ __launch_bounds__(256) void k_scan1(const int* __restrict__ deg, int n,
                                               int* __restrict__ excl,
                                               int* __restrict__ bsum) {
    __shared__ int sd[256];
    int t = threadIdx.x, i = blockIdx.x * 256 + t;
    int v = (i < n) ? deg[i] : 0;
    sd[t] = v;
    __syncthreads();
    for (int off = 1; off < 256; off <<= 1) {
        int u = (t >= off) ? sd[t - off] : 0;
        __syncthreads();
        sd[t] += u;
        __syncthreads();
    }
    if (i < n) excl[i] = sd[t] - v;
    if (t == 255) bsum[blockIdx.x] = sd[255];
}

__global__ __launch_bounds__(256) void k_scan3b(const int* __restrict__ deg,
                                                const int* __restrict__ excl,
                                                const int* __restrict__ bsum,
                                                int nbs, int n,
                                                int* __restrict__ row_ptr) {
    __shared__ int sd[256];
    int t = threadIdx.x;
    int v = (t < nbs) ? bsum[t] : 0;
    sd[t] = v;
    __syncthreads();
    for (int off = 1; off < 256; off <<= 1) {
        int u = (t >= off) ? sd[t - off] : 0;
        __syncthreads();
        sd[t] += u;
        __syncthreads();
    }
    int pref = (blockIdx.x == 0) ? 0 : sd[blockIdx.x - 1];
    int i = blockIdx.x * 256 + t;
    if (i < n) {
        int rp = pref + excl[i];
        row_ptr[i] = rp;
        if (i == n - 1) row_ptr[n] = rp + deg[i];
    }
}

// ---- pass 2: XCD-pinned placement into partition-confined CSR windows ----
__global__ __launch_bounds__(256) void k_place(const int4* __restrict__ tmp,
                                               const int* __restrict__ bstart,
                                               const int* __restrict__ bcnt,
                                               const int* __restrict__ row_ptr,
                                               int nchunk,
                                               int2* __restrict__ csr0,
                                               int2* __restrict__ csr1) {
    int xcd = blockIdx.x & 7;
    int j = blockIdx.x >> 3;  // 0..CB-1
    for (int ph = 0; ph < NPARTS / 8; ++ph) {
        int part = xcd + 8 * ph;
        for (int c = j; c < nchunk; c += CB) {
            int s = bstart[c * NPARTS + part];
            int cnt = bcnt[c * NPARTS + part];
            for (int i = threadIdx.x; i < cnt; i += 256) {
                int4 r = tmp[(size_t)s + i];
                int d = r.w & 0xffff;
                int rk = ((uint)r.w) >> 16;
                int pos = row_ptr[d] + rk;
                csr0[pos] = make_int2(r.x, r.y);
                csr1[pos] = make_int2(r.x, r.z);
            }
        }
    }
}

// ---- aggregation: one wave per node, single pass; rep packed bf16x2 ----
__global__ __launch_bounds__(512) void k_aggr(const uint* __restrict__ rep32,
                                              const int* __restrict__ row_ptr,
                                              const int2* __restrict__ csr,
                                              uint* __restrict__ xout, int n) {
    int wave = threadIdx.x >> 6, lane = threadIdx.x & 63;
    int node = blockIdx.x * 8 + wave;
    if (node >= n) return;
    int s0 = row_ptr[node], s1 = row_ptr[node + 1];
    float accx = 0.f, accy = 0.f, ssum = 0.f, amax = 0.f;
    int s = s0;
    for (; s + 8 <= s1; s += 8) {
        int2 c0 = csr[s], c1 = csr[s + 1], c2 = csr[s + 2], c3 = csr[s + 3];
        int2 c4 = csr[s + 4], c5 = csr[s + 5], c6 = csr[s + 6], c7 = csr[s + 7];
        float a0 = __int_as_float(c0.y), a1 = __int_as_float(c1.y);
        float a2 = __int_as_float(c2.y), a3 = __int_as_float(c3.y);
        float a4 = __int_as_float(c4.y), a5 = __int_as_float(c5.y);
        float a6 = __int_as_float(c6.y), a7 = __int_as_float(c7.y);
        uint r0 = rep32[(size_t)c0.x * 64 + lane];
        uint r1 = rep32[(size_t)c1.x * 64 + lane];
        uint r2 = rep32[(size_t)c2.x * 64 + lane];
        uint r3 = rep32[(size_t)c3.x * 64 + lane];
        uint r4 = rep32[(size_t)c4.x * 64 + lane];
        uint r5 = rep32[(size_t)c5.x * 64 + lane];
        uint r6 = rep32[(size_t)c6.x * 64 + lane];
        uint r7 = rep32[(size_t)c7.x * 64 + lane];
        ssum += a0 + a1 + a2 + a3 + a4 + a5 + a6 + a7;
        amax = fmaxf(amax, fmaxf(fmaxf(fmaxf(a0, a1), fmaxf(a2, a3)),
                                 fmaxf(fmaxf(a4, a5), fmaxf(a6, a7))));
        accx = fmaf(a0, bf2f(r0 & 0xffffu), accx);
        accy = fmaf(a0, bf2f(r0 >> 16), accy);
        accx = fmaf(a1, bf2f(r1 & 0xffffu), accx);
        accy = fmaf(a1, bf2f(r1 >> 16), accy);
        accx = fmaf(a2, bf2f(r2 & 0xffffu), accx);
        accy = fmaf(a2, bf2f(r2 >> 16), accy);
        accx = fmaf(a3, bf2f(r3 & 0xffffu), accx);
        accy = fmaf(a3, bf2f(r3 >> 16), accy);
        accx = fmaf(a4, bf2f(r4 & 0xffffu), accx);
        accy = fmaf(a4, bf2f(r4 >> 16), accy);
        accx = fmaf(a5, bf2f(r5 & 0xffffu), accx);
        accy = fmaf(a5, bf2f(r5 >> 16), accy);
        accx = fmaf(a6, bf2f(r6 & 0xffffu), accx);
        accy = fmaf(a6, bf2f(r6 >> 16), accy);
        accx = fmaf(a7, bf2f(r7 & 0xffffu), accx);
        accy = fmaf(a7, bf2f(r7 >> 16), accy);
    }
    for (; s < s1; ++s) {
        int2 c = csr[s];
        float a = __int_as_float(c.y);
        uint r = rep32[(size_t)c.x * 64 + lane];
        ssum += a;
        amax = fmaxf(amax, a);
        accx = fmaf(a, bf2f(r & 0xffffu), accx);
        accy = fmaf(a, bf2f(r >> 16), accy);
    }
    float inv = (s1 > s0) ? 1.f / (ssum + amax * 1e-16f) : 0.f;
    uint m = rep32[(size_t)node * 64 + lane];
    float ox = fmaf(accx, inv, bf2f(m & 0xffffu));
    float oy = fmaf(accy, inv, bf2f(m >> 16));
    xout[(size_t)node * 64 + lane] = f2bf(ox) | (f2bf(oy) << 16);
}

// ============================ dense MFMA kernels ============================
// 512 threads = 8 waves; wave handles 32 nodes (2 row-tiles of 16).
#define WROW 136  // shorts per LDS W row (128 + 8 pad -> 2-way banks = free)

// ---- MLP: rep(bf16) = LN(gelu(x(bf16) @ W^T + b)) ----
__global__ __launch_bounds__(512) void k_mlp(const uint* __restrict__ x32,
                                             const float* __restrict__ W,
                                             const float* __restrict__ b,
                                             const float* __restrict__ lw,
                                             const float* __restrict__ lb,
                                             uint* __restrict__ out32, int n) {
    __shared__ ushort Wbf[128 * WROW];
    uint* wd = (uint*)Wbf;
    for (int idx = threadIdx.x; idx < 128 * 64; idx += 512) {
        int row = idx >> 6, d = idx & 63;
        float2 w2 = *(const float2*)&W[row * 128 + d * 2];
        wd[row * (WROW / 2) + d] = f2bf(w2.x) | (f2bf(w2.y) << 16);
    }
    __syncthreads();
    int wv = threadIdx.x >> 6, l = threadIdx.x & 63;
    int c = l & 15, q = l >> 4;
    int base = blockIdx.x * 256 + wv * 32;
    int r0 = min(base + c, n - 1);
    int r1 = min(base + 16 + c, n - 1);

    f32x4 acc[2][8];
#pragma unroll
    for (int rt = 0; rt < 2; ++rt)
#pragma unroll
        for (int ct = 0; ct < 8; ++ct) acc[rt][ct] = (f32x4){0.f, 0.f, 0.f, 0.f};

#pragma unroll
    for (int kb = 0; kb < 4; ++kb) {
        ABu a0, a1;
        a0.u = *(const uint4*)&x32[(size_t)r0 * 64 + kb * 16 + q * 4];
        a1.u = *(const uint4*)&x32[(size_t)r1 * 64 + kb * 16 + q * 4];
#pragma unroll
        for (int ct = 0; ct < 8; ++ct) {
            bf16x8 bf = *(const bf16x8*)&Wbf[(ct * 16 + c) * WROW + kb * 32 + q * 8];
            acc[0][ct] = __builtin_amdgcn_mfma_f32_16x16x32_bf16(a0.v, bf, acc[0][ct], 0, 0, 0);
            acc[1][ct] = __builtin_amdgcn_mfma_f32_16x16x32_bf16(a1.v, bf, acc[1][ct], 0, 0, 0);
        }
    }

    float bias[8], lwv[8], lbv[8];
#pragma unroll
    for (int ct = 0; ct < 8; ++ct) {
        bias[ct] = b[ct * 16 + c];
        lwv[ct] = lw[ct * 16 + c];
        lbv[ct] = lb[ct * 16 + c];
    }

#pragma unroll
    for (int rt = 0; rt < 2; ++rt) {
#pragma unroll
        for (int ct = 0; ct < 8; ++ct)
#pragma unroll
            for (int i = 0; i < 4; ++i) {
                float h = acc[rt][ct][i] + bias[ct];
                acc[rt][ct][i] = 0.5f * h * (1.f + erff(h * 0.70710678118654752f));
            }
        float mu[4], rstd[4];
#pragma unroll
        for (int i = 0; i < 4; ++i) {
            float s = 0.f;
#pragma unroll
            for (int ct = 0; ct < 8; ++ct) s += acc[rt][ct][i];
            s += __shfl_xor(s, 1);
            s += __shfl_xor(s, 2);
            s += __shfl_xor(s, 4);
            s += __shfl_xor(s, 8);
            mu[i] = s * (1.f / 128.f);
        }
#pragma unroll
        for (int i = 0; i < 4; ++i) {
            float v = 0.f;
#pragma unroll
            for (int ct = 0; ct < 8; ++ct) {
                float d = acc[rt][ct][i] - mu[i];
                v += d * d;
            }
            v += __shfl_xor(v, 1);
            v += __shfl_xor(v, 2);
            v += __shfl_xor(v, 4);
            v += __shfl_xor(v, 8);
            rstd[i] = rsqrtf(v * (1.f / 128.f) + 1e-5f);
        }
#pragma unroll
        for (int ct = 0; ct < 8; ++ct)
#pragma unroll
            for (int i = 0; i < 4; ++i) {
                float o = (acc[rt][ct][i] - mu[i]) * rstd[i] * lwv[ct] + lbv[ct];
                float p = __shfl_xor(o, 1);
                uint dw = (c & 1) ? (f2bf(p) | (f2bf(o) << 16))
                                  : (f2bf(o) | (f2bf(p) << 16));
                int R = base + rt * 16 + q * 4 + i;
                if (R < n && (c & 1) == 0)
                    out32[(size_t)R * 64 + ct * 8 + (c >> 1)] = dw;
            }
    }
}

// ---- input projection: rep(bf16) = attr(f32) @ W^T + b ----
__global__ __launch_bounds__(512) void k_input(const float* __restrict__ attr,
                                               const float* __restrict__ W,
                                               const float* __restrict__ b,
                                               uint* __restrict__ out32, int n) {
    __shared__ ushort Wbf[128 * WROW];
    uint* wd = (uint*)Wbf;
    for (int idx = threadIdx.x; idx < 128 * 64; idx += 512) {
        int row = idx >> 6, d = idx & 63;
        float2 w2 = *(const float2*)&W[row * 128 + d * 2];
        wd[row * (WROW / 2) + d] = f2bf(w2.x) | (f2bf(w2.y) << 16);
    }
    __syncthreads();
    int wv = threadIdx.x >> 6, l = threadIdx.x & 63;
    int c = l & 15, q = l >> 4;
    int base = blockIdx.x * 256 + wv * 32;
    int r0 = min(base + c, n - 1);
    int r1 = min(base + 16 + c, n - 1);

    f32x4 acc[2][8];
#pragma unroll
    for (int rt = 0; rt < 2; ++rt)
#pragma unroll
        for (int ct = 0; ct < 8; ++ct) acc[rt][ct] = (f32x4){0.f, 0.f, 0.f, 0.f};

#pragma unroll
    for (int kb = 0; kb < 4; ++kb) {
        ABh a0, a1;
        float4 f0 = *(const float4*)&attr[(size_t)r0 * 128 + kb * 32 + q * 8];
        float4 f1 = *(const float4*)&attr[(size_t)r0 * 128 + kb * 32 + q * 8 + 4];
        a0.h[0] = f2bf(f0.x); a0.h[1] = f2bf(f0.y); a0.h[2] = f2bf(f0.z); a0.h[3] = f2bf(f0.w);
        a0.h[4] = f2bf(f1.x); a0.h[5] = f2bf(f1.y); a0.h[6] = f2bf(f1.z); a0.h[7] = f2bf(f1.w);
        float4 g0 = *(const float4*)&attr[(size_t)r1 * 128 + kb * 32 + q * 8];
        float4 g1 = *(const float4*)&attr[(size_t)r1 * 128 + kb * 32 + q * 8 + 4];
        a1.h[0] = f2bf(g0.x); a1.h[1] = f2bf(g0.y); a1.h[2] = f2bf(g0.z); a1.h[3] = f2bf(g0.w);
        a1.h[4] = f2bf(g1.x); a1.h[5] = f2bf(g1.y); a1.h[6] = f2bf(g1.z); a1.h[7] = f2bf(g1.w);
#pragma unroll
        for (int ct = 0; ct < 8; ++ct) {
            bf16x8 bf = *(const bf16x8*)&Wbf[(ct * 16 + c) * WROW + kb * 32 + q * 8];
            acc[0][ct] = __builtin_amdgcn_mfma_f32_16x16x32_bf16(a0.v, bf, acc[0][ct], 0, 0, 0);
            acc[1][ct] = __builtin_amdgcn_mfma_f32_16x16x32_bf16(a1.v, bf, acc[1][ct], 0, 0, 0);
        }
    }
    float bias[8];
#pragma unroll
    for (int ct = 0; ct < 8; ++ct) bias[ct] = b[ct * 16 + c];
#pragma unroll
    for (int rt = 0; rt < 2; ++rt)
#pragma unroll
        for (int ct = 0; ct < 8; ++ct)
#pragma unroll
            for (int i = 0; i < 4; ++i) {
                float o = acc[rt][ct][i] + bias[ct];
                float p = __shfl_xor(o, 1);
                uint dw = (c & 1) ? (f2bf(p) | (f2bf(o) << 16))
                                  : (f2bf(o) | (f2bf(p) << 16));
                int R = base + rt * 16 + q * 4 + i;
                if (R < n && (c & 1) == 0)
                    out32[(size_t)R * 64 + ct * 8 + (c >> 1)] = dw;
            }
}

// ---- output projection: out(f32) = rep(bf16) @ W_out^T + b_out (64 outs) ----
__global__ __launch_bounds__(512) void k_out(const uint* __restrict__ rep32,
                                             const float* __restrict__ W,
                                             const float* __restrict__ b,
                                             float* __restrict__ out, int n) {
    __shared__ ushort Wbf[64 * WROW];
    uint* wd = (uint*)Wbf;
    for (int idx = threadIdx.x; idx < 64 * 64; idx += 512) {
        int row = idx >> 6, d = idx & 63;
        float2 w2 = *(const float2*)&W[row * 128 + d * 2];
        wd[row * (WROW / 2) + d] = f2bf(w2.x) | (f2bf(w2.y) << 16);
    }
    __syncthreads();
    int wv = threadIdx.x >> 6, l = threadIdx.x & 63;
    int c = l & 15, q = l >> 4;
    int base = blockIdx.x * 256 + wv * 32;
    int r0 = min(base + c, n - 1);
    int r1 = min(base + 16 + c, n - 1);

    f32x4 acc[2][4];
#pragma unroll
    for (int rt = 0; rt < 2; ++rt)
#pragma unroll
        for (int ct = 0; ct < 4; ++ct) acc[rt][ct] = (f32x4){0.f, 0.f, 0.f, 0.f};

#pragma unroll
    for (int kb = 0; kb < 4; ++kb) {
        ABu a0, a1;
        a0.u = *(const uint4*)&rep32[(size_t)r0 * 64 + kb * 16 + q * 4];
        a1.u = *(const uint4*)&rep32[(size_t)r1 * 64 + kb * 16 + q * 4];
#pragma unroll
        for (int ct = 0; ct < 4; ++ct) {
            bf16x8 bf = *(const bf16x8*)&Wbf[(ct * 16 + c) * WROW + kb * 32 + q * 8];
            acc[0][ct] = __builtin_amdgcn_mfma_f32_16x16x32_bf16(a0.v, bf, acc[0][ct], 0, 0, 0);
            acc[1][ct] = __builtin_amdgcn_mfma_f32_16x16x32_bf16(a1.v, bf, acc[1][ct], 0, 0, 0);
        }
    }
    float bias[4];
#pragma unroll
    for (int ct = 0; ct < 4; ++ct) bias[ct] = b[ct * 16 + c];
#pragma unroll
    for (int rt = 0; rt < 2; ++rt)
#pragma unroll
        for (int ct = 0; ct < 4; ++ct)
#pragma unroll
            for (int i = 0; i < 4; ++i) {
                int R = base + rt * 16 + q * 4 + i;
                if (R < n) out[(size_t)R * 64 + ct * 16 + c] = acc[rt][ct][i] + bias[ct];
            }
}

extern "C" void kernel_launch(void* const* d_in, const int* in_sizes, int n_in,
                              void* d_out, int out_size, void* d_ws, size_t ws_size,
                              hipStream_t stream) {
    const float* node_attr = (const float*)d_in[0];
    const int* ei = (const int*)d_in[1];
    // d_in[2] = batch_idx (unused)
    const float* adv = (const float*)d_in[3];
    const float* W_inp = (const float*)d_in[4];
    const float* b_inp = (const float*)d_in[5];
    const float* W_a = (const float*)d_in[6];
    const float* b_a = (const float*)d_in[7];
    const float* ln_w = (const float*)d_in[8];
    const float* ln_b = (const float*)d_in[9];
    const float* W_out = (const float*)d_in[10];
    const float* b_out = (const float*)d_in[11];

    const int n = in_sizes[0] / 128;
    const int E = in_sizes[1] / 2;
    const int nchunk = (E + CHUNKE - 1) / CHUNKE;
    const int PART = (n + NPARTS - 1) / NPARTS;

    // workspace: csr0,csr1 (E int2 each) | tmp (E int4; A,B overlay after
    // k_place: n*64 dwords each, 2*n*64*4 == E*16 here) | misc
    int2* csr0 = (int2*)d_ws;
    int2* csr1 = csr0 + E;
    int4* tmp = (int4*)(csr1 + E);
    uint* A = (uint*)tmp;      // overlays tmp (dead after k_place)
    uint* B = A + (size_t)n * 64;
    int* deg = (int*)(tmp + E);
    int* excl = deg + n;
    int* row_ptr = excl + n;           // n+1
    int* bsum = row_ptr + n + 1;       // 256
    int* bstart = bsum + 256;          // nchunk*NPARTS
    int* bcnt = bstart + (size_t)nchunk * NPARTS;

    const int* src = ei;
    const int* dst = ei + E;

    hipMemsetAsync(deg, 0, (size_t)n * sizeof(int), stream);

    int nbs = (n + 255) / 256;  // n <= 65536
    k_bin<<<nchunk, 256, 0, stream>>>(src, dst, adv, E, PART, deg, tmp, bstart, bcnt);
    k_scan1<<<nbs, 256, 0, stream>>>(deg, n, excl, bsum);
    k_scan3b<<<nbs, 256, 0, stream>>>(deg, excl, bsum, nbs, n, row_ptr);
    k_place<<<8 * CB, 256, 0, stream>>>(tmp, bstart, bcnt, row_ptr, nchunk, csr0, csr1);

    int nbd = (n + 255) / 256;  // dense kernels: 256 nodes/block
    int nb8 = (n + 7) / 8;
    k_input<<<nbd, 512, 0, stream>>>(node_attr, W_inp, b_inp, A, n);

    // layer 0: B = aggr(A); A = mlp(B)
    k_aggr<<<nb8, 512, 0, stream>>>(A, row_ptr, csr0, B, n);
    k_mlp<<<nbd, 512, 0, stream>>>(B, W_a, b_a, ln_w, ln_b, A, n);
    // layer 1: B = aggr(A); A = mlp(B)
    k_aggr<<<nb8, 512, 0, stream>>>(A, row_ptr, csr1, B, n);
    k_mlp<<<nbd, 512, 0, stream>>>(B, W_a + 128 * 128, b_a + 128,
                                   ln_w + 128, ln_b + 128, A, n);

    k_out<<<nbd, 512, 0, stream>>>(A, W_out, b_out, (float*)d_out, n);
}

// Round 11
// 305.412 us; speedup vs baseline: 10.5364x; 1.0450x over previous
//
#include <hip/hip_runtime.h>
#include <hip/hip_bf16.h>
#include <math.h>

// ---------------------------------------------------------------------------
// GNN: rep = attr @ W_inp^T + b
//      2x { x = (segsoftmax-weighted aggr of rep[src] by dst) + rep;
//           rep = LN(gelu(x @ W_a^T + b)) }
//      out = rep @ W_out^T + b_out
// segment_softmax(log a) == a / (ssum + amax*1e-16) -> per-node scalar.
// CSR build (per call), all edge streams read exactly once:
//   k_bin:   single pass, 512 thr (LDS 64KB caps 2 blk/CU -> need 8 waves/blk
//            for latency hiding); rank = atomicAdd(&deg[dst]) inline; LDS
//            histogram + wave-parallel scan + reorder by 32 dst-parts;
//            records (src,a0,a1,dst|rank<<16) flushed coalesced to tmp.
//   scan:    scan1 (per-256 blocks) + scan3b (redundant scan of bsums).
//   k_place: XCD-pinned blocks read partition segments sequentially, compute
//            pos=row_ptr[dst]+rank, write csr0/csr1[pos] confined to ~0.8MB
//            windows per XCD -> L2 line merging.
// k_aggr: 16-deep gather unroll (static indices), 8B records/edge/layer.
// Node features packed bf16x2; dense layers bf16 MFMA with fused GELU/LN.
// ---------------------------------------------------------------------------

#define WAVE 64
#define NPARTS 32
#define CHUNKE 4096
#define CB 64   // chunk-parallel blocks per xcd-lane in k_place

typedef __attribute__((ext_vector_type(8))) short bf16x8;
typedef __attribute__((ext_vector_type(4))) float f32x4;
union ABu { uint4 u; bf16x8 v; };
union ABh { ushort h[8]; bf16x8 v; };

static __device__ __forceinline__ float bf2f(uint u16) {
    union { uint i; float f; } c;
    c.i = u16 << 16;
    return c.f;
}
static __device__ __forceinline__ uint f2bf(float f) {
    uint x = __float_as_uint(f);
    return (x + 0x7FFFu + ((x >> 16) & 1u)) >> 16;  // RNE
}

// ---- pass 1: chunk-local LDS sort by dst partition; rank computed inline ----
__global__ __launch_bounds__(512) void k_bin(const int* __restrict__ src,
                                             const int* __restrict__ dst,
                                             const float* __restrict__ adv,
                                             int E, int PART,
                                             int* __restrict__ deg,
                                             int4* __restrict__ tmp,
                                             int* __restrict__ bstart,
                                             int* __restrict__ bcnt) {
    __shared__ int hist[NPARTS], cur[NPARTS], base_[NPARTS];
    __shared__ int4 buf[CHUNKE];
    int c = blockIdx.x;
    int e0 = c * CHUNKE;
    int cnt = min(CHUNKE, E - e0);
    int dreg[CHUNKE / 512];
    int preg[CHUNKE / 512];
    if (threadIdx.x < NPARTS) hist[threadIdx.x] = 0;
    __syncthreads();
#pragma unroll
    for (int i = 0; i < CHUNKE / 512; ++i) {
        int idx = threadIdx.x + i * 512;
        if (idx < cnt) {
            int d = dst[e0 + idx];
            int pt = d / PART;
            dreg[i] = d;
            preg[i] = pt;
            atomicAdd(&hist[pt], 1);
        }
    }
    __syncthreads();
    if (threadIdx.x < 64) {
        int t = threadIdx.x;
        int v = (t < NPARTS) ? hist[t] : 0;
#pragma unroll
        for (int off = 1; off < NPARTS; off <<= 1) {
            int u = __shfl_up(v, off);
            if (t >= off) v += u;
        }
        if (t < NPARTS) {
            base_[t] = v - hist[t];
            cur[t] = v - hist[t];
        }
    }
    __syncthreads();
#pragma unroll
    for (int i = 0; i < CHUNKE / 512; ++i) {
        int idx = threadIdx.x + i * 512;
        if (idx < cnt) {
            int e = e0 + idx;
            int slot = atomicAdd(&cur[preg[i]], 1);
            int rk = atomicAdd(&deg[dreg[i]], 1);  // rank within row (any order)
            buf[slot] = make_int4(src[e], __float_as_int(adv[e]),
                                  __float_as_int(adv[E + e]),
                                  dreg[i] | (rk << 16));
        }
    }
    __syncthreads();
    for (int i = threadIdx.x; i < cnt; i += 512) tmp[(size_t)e0 + i] = buf[i];
    if (threadIdx.x < NPARTS) {
        bstart[c * NPARTS + threadIdx.x] = e0 + base_[threadIdx.x];
        bcnt[c * NPARTS + threadIdx.x] = hist[threadIdx.x];
    }
}

// ---- scan: per-256-chunk scan, then per-block redundant scan of bsums ----
__global__ __launch_bounds__(256) void k_scan1(const int* __restrict__ deg, int n,
                                               int* __restrict__ excl,
                                               int* __restrict__ bsum) {
    __shared__ int sd[256];
    int t = threadIdx.x, i = blockIdx.x * 256 + t;
    int v = (i < n) ? deg[i] : 0;
    sd[t] = v;
    __syncthreads();
    for (int off = 1; off < 256; off <<= 1) {
        int u = (t >= off) ? sd[t - off] : 0;
        __syncthreads();
        sd[t] += u;
        __syncthreads();
    }
    if (i < n) excl[i] = sd[t] - v;
    if (t == 255) bsum[blockIdx.x] = sd[255];
}

__global__ __launch_bounds__(256) void k_scan3b(const int* __restrict__ deg,
                                                const int* __restrict__ excl,
                                                const int* __restrict__ bsum,
                                                int nbs, int n,
                                                int* __restrict__ row_ptr) {
    __shared__ int sd[256];
    int t = threadIdx.x;
    int v = (t < nbs) ? bsum[t] : 0;
    sd[t] = v;
    __syncthreads();
    for (int off = 1; off < 256; off <<= 1) {
        int u = (t >= off) ? sd[t - off] : 0;
        __syncthreads();
        sd[t] += u;
        __syncthreads();
    }
    int pref = (blockIdx.x == 0) ? 0 : sd[blockIdx.x - 1];
    int i = blockIdx.x * 256 + t;
    if (i < n) {
        int rp = pref + excl[i];
        row_ptr[i] = rp;
        if (i == n - 1) row_ptr[n] = rp + deg[i];
    }
}

// ---- pass 2: XCD-pinned placement into partition-confined CSR windows ----
__global__ __launch_bounds__(256) void k_place(const int4* __restrict__ tmp,
                                               const int* __restrict__ bstart,
                                               const int* __restrict__ bcnt,
                                               const int* __restrict__ row_ptr,
                                               int nchunk,
                                               int2* __restrict__ csr0,
                                               int2* __restrict__ csr1) {
    int xcd = blockIdx.x & 7;
    int j = blockIdx.x >> 3;  // 0..CB-1
    for (int ph = 0; ph < NPARTS / 8; ++ph) {
        int part = xcd + 8 * ph;
        for (int c = j; c < nchunk; c += CB) {
            int s = bstart[c * NPARTS + part];
            int cnt = bcnt[c * NPARTS + part];
            for (int i = threadIdx.x; i < cnt; i += 256) {
                int4 r = tmp[(size_t)s + i];
                int d = r.w & 0xffff;
                int rk = ((uint)r.w) >> 16;
                int pos = row_ptr[d] + rk;
                csr0[pos] = make_int2(r.x, r.y);
                csr1[pos] = make_int2(r.x, r.z);
            }
        }
    }
}

// ---- aggregation: one wave per node, 16-deep gather unroll ----
__global__ __launch_bounds__(512) void k_aggr(const uint* __restrict__ rep32,
                                              const int* __restrict__ row_ptr,
                                              const int2* __restrict__ csr,
                                              uint* __restrict__ xout, int n) {
    int wave = threadIdx.x >> 6, lane = threadIdx.x & 63;
    int node = blockIdx.x * 8 + wave;
    if (node >= n) return;
    int s0 = row_ptr[node], s1 = row_ptr[node + 1];
    float accx = 0.f, accy = 0.f, ssum = 0.f, amax = 0.f;
    int s = s0;
    for (; s + 16 <= s1; s += 16) {
        int2 cc[16];
        uint rr[16];
#pragma unroll
        for (int k = 0; k < 16; ++k) cc[k] = csr[s + k];
#pragma unroll
        for (int k = 0; k < 16; ++k) rr[k] = rep32[(size_t)cc[k].x * 64 + lane];
#pragma unroll
        for (int k = 0; k < 16; ++k) {
            float a = __int_as_float(cc[k].y);
            ssum += a;
            amax = fmaxf(amax, a);
            accx = fmaf(a, bf2f(rr[k] & 0xffffu), accx);
            accy = fmaf(a, bf2f(rr[k] >> 16), accy);
        }
    }
    for (; s + 4 <= s1; s += 4) {
        int2 cc[4];
        uint rr[4];
#pragma unroll
        for (int k = 0; k < 4; ++k) cc[k] = csr[s + k];
#pragma unroll
        for (int k = 0; k < 4; ++k) rr[k] = rep32[(size_t)cc[k].x * 64 + lane];
#pragma unroll
        for (int k = 0; k < 4; ++k) {
            float a = __int_as_float(cc[k].y);
            ssum += a;
            amax = fmaxf(amax, a);
            accx = fmaf(a, bf2f(rr[k] & 0xffffu), accx);
            accy = fmaf(a, bf2f(rr[k] >> 16), accy);
        }
    }
    for (; s < s1; ++s) {
        int2 c = csr[s];
        float a = __int_as_float(c.y);
        uint r = rep32[(size_t)c.x * 64 + lane];
        ssum += a;
        amax = fmaxf(amax, a);
        accx = fmaf(a, bf2f(r & 0xffffu), accx);
        accy = fmaf(a, bf2f(r >> 16), accy);
    }
    float inv = (s1 > s0) ? 1.f / (ssum + amax * 1e-16f) : 0.f;
    uint m = rep32[(size_t)node * 64 + lane];
    float ox = fmaf(accx, inv, bf2f(m & 0xffffu));
    float oy = fmaf(accy, inv, bf2f(m >> 16));
    xout[(size_t)node * 64 + lane] = f2bf(ox) | (f2bf(oy) << 16);
}

// ============================ dense MFMA kernels ============================
// 512 threads = 8 waves; wave handles 32 nodes (2 row-tiles of 16).
#define WROW 136  // shorts per LDS W row (128 + 8 pad -> 2-way banks = free)

// ---- MLP: rep(bf16) = LN(gelu(x(bf16) @ W^T + b)) ----
__global__ __launch_bounds__(512) void k_mlp(const uint* __restrict__ x32,
                                             const float* __restrict__ W,
                                             const float* __restrict__ b,
                                             const float* __restrict__ lw,
                                             const float* __restrict__ lb,
                                             uint* __restrict__ out32, int n) {
    __shared__ ushort Wbf[128 * WROW];
    uint* wd = (uint*)Wbf;
    for (int idx = threadIdx.x; idx < 128 * 64; idx += 512) {
        int row = idx >> 6, d = idx & 63;
        float2 w2 = *(const float2*)&W[row * 128 + d * 2];
        wd[row * (WROW / 2) + d] = f2bf(w2.x) | (f2bf(w2.y) << 16);
    }
    __syncthreads();
    int wv = threadIdx.x >> 6, l = threadIdx.x & 63;
    int c = l & 15, q = l >> 4;
    int base = blockIdx.x * 256 + wv * 32;
    int r0 = min(base + c, n - 1);
    int r1 = min(base + 16 + c, n - 1);

    f32x4 acc[2][8];
#pragma unroll
    for (int rt = 0; rt < 2; ++rt)
#pragma unroll
        for (int ct = 0; ct < 8; ++ct) acc[rt][ct] = (f32x4){0.f, 0.f, 0.f, 0.f};

#pragma unroll
    for (int kb = 0; kb < 4; ++kb) {
        ABu a0, a1;
        a0.u = *(const uint4*)&x32[(size_t)r0 * 64 + kb * 16 + q * 4];
        a1.u = *(const uint4*)&x32[(size_t)r1 * 64 + kb * 16 + q * 4];
#pragma unroll
        for (int ct = 0; ct < 8; ++ct) {
            bf16x8 bf = *(const bf16x8*)&Wbf[(ct * 16 + c) * WROW + kb * 32 + q * 8];
            acc[0][ct] = __builtin_amdgcn_mfma_f32_16x16x32_bf16(a0.v, bf, acc[0][ct], 0, 0, 0);
            acc[1][ct] = __builtin_amdgcn_mfma_f32_16x16x32_bf16(a1.v, bf, acc[1][ct], 0, 0, 0);
        }
    }

    float bias[8], lwv[8], lbv[8];
#pragma unroll
    for (int ct = 0; ct < 8; ++ct) {
        bias[ct] = b[ct * 16 + c];
        lwv[ct] = lw[ct * 16 + c];
        lbv[ct] = lb[ct * 16 + c];
    }

#pragma unroll
    for (int rt = 0; rt < 2; ++rt) {
#pragma unroll
        for (int ct = 0; ct < 8; ++ct)
#pragma unroll
            for (int i = 0; i < 4; ++i) {
                float h = acc[rt][ct][i] + bias[ct];
                acc[rt][ct][i] = 0.5f * h * (1.f + erff(h * 0.70710678118654752f));
            }
        float mu[4], rstd[4];
#pragma unroll
        for (int i = 0; i < 4; ++i) {
            float s = 0.f;
#pragma unroll
            for (int ct = 0; ct < 8; ++ct) s += acc[rt][ct][i];
            s += __shfl_xor(s, 1);
            s += __shfl_xor(s, 2);
            s += __shfl_xor(s, 4);
            s += __shfl_xor(s, 8);
            mu[i] = s * (1.f / 128.f);
        }
#pragma unroll
        for (int i = 0; i < 4; ++i) {
            float v = 0.f;
#pragma unroll
            for (int ct = 0; ct < 8; ++ct) {
                float d = acc[rt][ct][i] - mu[i];
                v += d * d;
            }
            v += __shfl_xor(v, 1);
            v += __shfl_xor(v, 2);
            v += __shfl_xor(v, 4);
            v += __shfl_xor(v, 8);
            rstd[i] = rsqrtf(v * (1.f / 128.f) + 1e-5f);
        }
#pragma unroll
        for (int ct = 0; ct < 8; ++ct)
#pragma unroll
            for (int i = 0; i < 4; ++i) {
                float o = (acc[rt][ct][i] - mu[i]) * rstd[i] * lwv[ct] + lbv[ct];
                float p = __shfl_xor(o, 1);
                uint dw = (c & 1) ? (f2bf(p) | (f2bf(o) << 16))
                                  : (f2bf(o) | (f2bf(p) << 16));
                int R = base + rt * 16 + q * 4 + i;
                if (R < n && (c & 1) == 0)
                    out32[(size_t)R * 64 + ct * 8 + (c >> 1)] = dw;
            }
    }
}

// ---- input projection: rep(bf16) = attr(f32) @ W^T + b ----
__global__ __launch_bounds__(512) void k_input(const float* __restrict__ attr,
                                               const float* __restrict__ W,
                                               const float* __restrict__ b,
                                               uint* __restrict__ out32, int n) {
    __shared__ ushort Wbf[128 * WROW];
    uint* wd = (uint*)Wbf;
    for (int idx = threadIdx.x; idx < 128 * 64; idx += 512) {
        int row = idx >> 6, d = idx & 63;
        float2 w2 = *(const float2*)&W[row * 128 + d * 2];
        wd[row * (WROW / 2) + d] = f2bf(w2.x) | (f2bf(w2.y) << 16);
    }
    __syncthreads();
    int wv = threadIdx.x >> 6, l = threadIdx.x & 63;
    int c = l & 15, q = l >> 4;
    int base = blockIdx.x * 256 + wv * 32;
    int r0 = min(base + c, n - 1);
    int r1 = min(base + 16 + c, n - 1);

    f32x4 acc[2][8];
#pragma unroll
    for (int rt = 0; rt < 2; ++rt)
#pragma unroll
        for (int ct = 0; ct < 8; ++ct) acc[rt][ct] = (f32x4){0.f, 0.f, 0.f, 0.f};

#pragma unroll
    for (int kb = 0; kb < 4; ++kb) {
        ABh a0, a1;
        float4 f0 = *(const float4*)&attr[(size_t)r0 * 128 + kb * 32 + q * 8];
        float4 f1 = *(const float4*)&attr[(size_t)r0 * 128 + kb * 32 + q * 8 + 4];
        a0.h[0] = f2bf(f0.x); a0.h[1] = f2bf(f0.y); a0.h[2] = f2bf(f0.z); a0.h[3] = f2bf(f0.w);
        a0.h[4] = f2bf(f1.x); a0.h[5] = f2bf(f1.y); a0.h[6] = f2bf(f1.z); a0.h[7] = f2bf(f1.w);
        float4 g0 = *(const float4*)&attr[(size_t)r1 * 128 + kb * 32 + q * 8];
        float4 g1 = *(const float4*)&attr[(size_t)r1 * 128 + kb * 32 + q * 8 + 4];
        a1.h[0] = f2bf(g0.x); a1.h[1] = f2bf(g0.y); a1.h[2] = f2bf(g0.z); a1.h[3] = f2bf(g0.w);
        a1.h[4] = f2bf(g1.x); a1.h[5] = f2bf(g1.y); a1.h[6] = f2bf(g1.z); a1.h[7] = f2bf(g1.w);
#pragma unroll
        for (int ct = 0; ct < 8; ++ct) {
            bf16x8 bf = *(const bf16x8*)&Wbf[(ct * 16 + c) * WROW + kb * 32 + q * 8];
            acc[0][ct] = __builtin_amdgcn_mfma_f32_16x16x32_bf16(a0.v, bf, acc[0][ct], 0, 0, 0);
            acc[1][ct] = __builtin_amdgcn_mfma_f32_16x16x32_bf16(a1.v, bf, acc[1][ct], 0, 0, 0);
        }
    }
    float bias[8];
#pragma unroll
    for (int ct = 0; ct < 8; ++ct) bias[ct] = b[ct * 16 + c];
#pragma unroll
    for (int rt = 0; rt < 2; ++rt)
#pragma unroll
        for (int ct = 0; ct < 8; ++ct)
#pragma unroll
            for (int i = 0; i < 4; ++i) {
                float o = acc[rt][ct][i] + bias[ct];
                float p = __shfl_xor(o, 1);
                uint dw = (c & 1) ? (f2bf(p) | (f2bf(o) << 16))
                                  : (f2bf(o) | (f2bf(p) << 16));
                int R = base + rt * 16 + q * 4 + i;
                if (R < n && (c & 1) == 0)
                    out32[(size_t)R * 64 + ct * 8 + (c >> 1)] = dw;
            }
}

// ---- output projection: out(f32) = rep(bf16) @ W_out^T + b_out (64 outs) ----
__global__ __launch_bounds__(512) void k_out(const uint* __restrict__ rep32,
                                             const float* __restrict__ W,
                                             const float* __restrict__ b,
                                             float* __restrict__ out, int n) {
    __shared__ ushort Wbf[64 * WROW];
    uint* wd = (uint*)Wbf;
    for (int idx = threadIdx.x; idx < 64 * 64; idx += 512) {
        int row = idx >> 6, d = idx & 63;
        float2 w2 = *(const float2*)&W[row * 128 + d * 2];
        wd[row * (WROW / 2) + d] = f2bf(w2.x) | (f2bf(w2.y) << 16);
    }
    __syncthreads();
    int wv = threadIdx.x >> 6, l = threadIdx.x & 63;
    int c = l & 15, q = l >> 4;
    int base = blockIdx.x * 256 + wv * 32;
    int r0 = min(base + c, n - 1);
    int r1 = min(base + 16 + c, n - 1);

    f32x4 acc[2][4];
#pragma unroll
    for (int rt = 0; rt < 2; ++rt)
#pragma unroll
        for (int ct = 0; ct < 4; ++ct) acc[rt][ct] = (f32x4){0.f, 0.f, 0.f, 0.f};

#pragma unroll
    for (int kb = 0; kb < 4; ++kb) {
        ABu a0, a1;
        a0.u = *(const uint4*)&rep32[(size_t)r0 * 64 + kb * 16 + q * 4];
        a1.u = *(const uint4*)&rep32[(size_t)r1 * 64 + kb * 16 + q * 4];
#pragma unroll
        for (int ct = 0; ct < 4; ++ct) {
            bf16x8 bf = *(const bf16x8*)&Wbf[(ct * 16 + c) * WROW + kb * 32 + q * 8];
            acc[0][ct] = __builtin_amdgcn_mfma_f32_16x16x32_bf16(a0.v, bf, acc[0][ct], 0, 0, 0);
            acc[1][ct] = __builtin_amdgcn_mfma_f32_16x16x32_bf16(a1.v, bf, acc[1][ct], 0, 0, 0);
        }
    }
    float bias[4];
#pragma unroll
    for (int ct = 0; ct < 4; ++ct) bias[ct] = b[ct * 16 + c];
#pragma unroll
    for (int rt = 0; rt < 2; ++rt)
#pragma unroll
        for (int ct = 0; ct < 4; ++ct)
#pragma unroll
            for (int i = 0; i < 4; ++i) {
                int R = base + rt * 16 + q * 4 + i;
                if (R < n) out[(size_t)R * 64 + ct * 16 + c] = acc[rt][ct][i] + bias[ct];
            }
}

extern "C" void kernel_launch(void* const* d_in, const int* in_sizes, int n_in,
                              void* d_out, int out_size, void* d_ws, size_t ws_size,
                              hipStream_t stream) {
    const float* node_attr = (const float*)d_in[0];
    const int* ei = (const int*)d_in[1];
    // d_in[2] = batch_idx (unused)
    const float* adv = (const float*)d_in[3];
    const float* W_inp = (const float*)d_in[4];
    const float* b_inp = (const float*)d_in[5];
    const float* W_a = (const float*)d_in[6];
    const float* b_a = (const float*)d_in[7];
    const float* ln_w = (const float*)d_in[8];
    const float* ln_b = (const float*)d_in[9];
    const float* W_out = (const float*)d_in[10];
    const float* b_out = (const float*)d_in[11];

    const int n = in_sizes[0] / 128;
    const int E = in_sizes[1] / 2;
    const int nchunk = (E + CHUNKE - 1) / CHUNKE;
    const int PART = (n + NPARTS - 1) / NPARTS;

    // workspace: csr0,csr1 (E int2 each) | tmp (E int4; A,B overlay after
    // k_place: n*64 dwords each, 2*n*64*4 == E*16 here) | misc
    int2* csr0 = (int2*)d_ws;
    int2* csr1 = csr0 + E;
    int4* tmp = (int4*)(csr1 + E);
    uint* A = (uint*)tmp;      // overlays tmp (dead after k_place)
    uint* B = A + (size_t)n * 64;
    int* deg = (int*)(tmp + E);
    int* excl = deg + n;
    int* row_ptr = excl + n;           // n+1
    int* bsum = row_ptr + n + 1;       // 256
    int* bstart = bsum + 256;          // nchunk*NPARTS
    int* bcnt = bstart + (size_t)nchunk * NPARTS;

    const int* src = ei;
    const int* dst = ei + E;

    hipMemsetAsync(deg, 0, (size_t)n * sizeof(int), stream);

    int nbs = (n + 255) / 256;  // n <= 65536
    k_bin<<<nchunk, 512, 0, stream>>>(src, dst, adv, E, PART, deg, tmp, bstart, bcnt);
    k_scan1<<<nbs, 256, 0, stream>>>(deg, n, excl, bsum);
    k_scan3b<<<nbs, 256, 0, stream>>>(deg, excl, bsum, nbs, n, row_ptr);
    k_place<<<8 * CB, 256, 0, stream>>>(tmp, bstart, bcnt, row_ptr, nchunk, csr0, csr1);

    int nbd = (n + 255) / 256;  // dense kernels: 256 nodes/block
    int nb8 = (n + 7) / 8;
    k_input<<<nbd, 512, 0, stream>>>(node_attr, W_inp, b_inp, A, n);

    // layer 0: B = aggr(A); A = mlp(B)
    k_aggr<<<nb8, 512, 0, stream>>>(A, row_ptr, csr0, B, n);
    k_mlp<<<nbd, 512, 0, stream>>>(B, W_a, b_a, ln_w, ln_b, A, n);
    // layer 1: B = aggr(A); A = mlp(B)
    k_aggr<<<nb8, 512, 0, stream>>>(A, row_ptr, csr1, B, n);
    k_mlp<<<nbd, 512, 0, stream>>>(B, W_a + 128 * 128, b_a + 128,
                                   ln_w + 128, ln_b + 128, A, n);

    k_out<<<nbd, 512, 0, stream>>>(A, W_out, b_out, (float*)d_out, n);
}

// Round 12
// 278.765 us; speedup vs baseline: 11.5436x; 1.0956x over previous
//
#include <hip/hip_runtime.h>
#include <hip/hip_bf16.h>
#include <math.h>

// ---------------------------------------------------------------------------
// GNN: rep = attr @ W_inp^T + b
//      2x { x = (segsoftmax-weighted aggr of rep[src] by dst) + rep;
//           rep = LN(gelu(x @ W_a^T + b)) }
//      out = rep @ W_out^T + b_out
// segment_softmax(log a) == a / (ssum + amax*1e-16) -> per-node scalar.
// CSR build with ZERO per-edge global atomics (1.6M random atomic RMWs were
// the round-10 wall: random 4B atomics ~ a full gather pass):
//   k_bin:   LDS partition-sort of 4096-edge chunks -> tmp(src,a0,a1,dst),
//            bstart/bcnt per (chunk,part). LDS atomics only.
//   k_deg:   256 blocks = (part, chunk-range); private LDS histogram of the
//            range's segments -> histg[part*8+r][*]. No global atomics.
//   scan1:   deg[i] = sum_r histg -> block scan -> bsum.
//   scan3b:  row_ptr; histg converted IN PLACE to rbase[part*8+r][dst] =
//            row_ptr + prefix over ranges.
//   k_place: same (part,range) blocks; LDS cursor from rbase, LDS-atomic++
//            gives unique positions (ranges own disjoint row sub-segments);
//            part=blockIdx&31 => all 8 ranges of a part on one XCD ->
//            csr writes confined & L2-merged.
// Node features packed bf16x2; dense layers bf16 MFMA with fused GELU/LN.
// ---------------------------------------------------------------------------

#define WAVE 64
#define NPARTS 32
#define CHUNKE 4096
#define PARTMAX 2048

typedef __attribute__((ext_vector_type(8))) short bf16x8;
typedef __attribute__((ext_vector_type(4))) float f32x4;
union ABu { uint4 u; bf16x8 v; };
union ABh { ushort h[8]; bf16x8 v; };

static __device__ __forceinline__ float bf2f(uint u16) {
    union { uint i; float f; } c;
    c.i = u16 << 16;
    return c.f;
}
static __device__ __forceinline__ uint f2bf(float f) {
    uint x = __float_as_uint(f);
    return (x + 0x7FFFu + ((x >> 16) & 1u)) >> 16;  // RNE
}

// ---- pass 1: chunk-local LDS sort by dst partition (LDS atomics only) ----
__global__ __launch_bounds__(512) void k_bin(const int* __restrict__ src,
                                             const int* __restrict__ dst,
                                             const float* __restrict__ adv,
                                             int E, int PART,
                                             int4* __restrict__ tmp,
                                             int* __restrict__ bstart,
                                             int* __restrict__ bcnt) {
    __shared__ int hist[NPARTS], cur[NPARTS], base_[NPARTS];
    __shared__ int4 buf[CHUNKE];
    int c = blockIdx.x;
    int e0 = c * CHUNKE;
    int cnt = min(CHUNKE, E - e0);
    int dreg[CHUNKE / 512];
    int preg[CHUNKE / 512];
    if (threadIdx.x < NPARTS) hist[threadIdx.x] = 0;
    __syncthreads();
#pragma unroll
    for (int i = 0; i < CHUNKE / 512; ++i) {
        int idx = threadIdx.x + i * 512;
        if (idx < cnt) {
            int d = dst[e0 + idx];
            int pt = d / PART;
            dreg[i] = d;
            preg[i] = pt;
            atomicAdd(&hist[pt], 1);
        }
    }
    __syncthreads();
    if (threadIdx.x < 64) {
        int t = threadIdx.x;
        int v = (t < NPARTS) ? hist[t] : 0;
#pragma unroll
        for (int off = 1; off < NPARTS; off <<= 1) {
            int u = __shfl_up(v, off);
            if (t >= off) v += u;
        }
        if (t < NPARTS) {
            base_[t] = v - hist[t];
            cur[t] = v - hist[t];
        }
    }
    __syncthreads();
#pragma unroll
    for (int i = 0; i < CHUNKE / 512; ++i) {
        int idx = threadIdx.x + i * 512;
        if (idx < cnt) {
            int e = e0 + idx;
            int slot = atomicAdd(&cur[preg[i]], 1);
            buf[slot] = make_int4(src[e], __float_as_int(adv[e]),
                                  __float_as_int(adv[E + e]), dreg[i]);
        }
    }
    __syncthreads();
    for (int i = threadIdx.x; i < cnt; i += 512) tmp[(size_t)e0 + i] = buf[i];
    if (threadIdx.x < NPARTS) {
        bstart[c * NPARTS + threadIdx.x] = e0 + base_[threadIdx.x];
        bcnt[c * NPARTS + threadIdx.x] = hist[threadIdx.x];
    }
}

// ---- pass 2: per-(part,range) private LDS histogram -> histg ----
__global__ __launch_bounds__(256) void k_deg(const int4* __restrict__ tmp,
                                             const int* __restrict__ bstart,
                                             const int* __restrict__ bcnt,
                                             int nchunk, int crange, int PART, int n,
                                             int* __restrict__ histg) {
    __shared__ int h[PARTMAX];
    int part = blockIdx.x & 31, r = blockIdx.x >> 5;
    for (int j = threadIdx.x; j < PART; j += 256) h[j] = 0;
    __syncthreads();
    int c0 = r * crange, c1 = min(c0 + crange, nchunk);
    int lo = part * PART;
    for (int c = c0; c < c1; ++c) {
        int s = bstart[c * NPARTS + part];
        int cnt = bcnt[c * NPARTS + part];
        for (int i = threadIdx.x; i < cnt; i += 256)
            atomicAdd(&h[tmp[(size_t)s + i].w - lo], 1);
    }
    __syncthreads();
    for (int j = threadIdx.x; j < PART; j += 256)
        histg[(size_t)(part * 8 + r) * PART + j] = h[j];
}

// ---- scan: deg = sum_r histg; per-256 block scan ----
__global__ __launch_bounds__(256) void k_scan1(const int* __restrict__ histg,
                                               int PART, int n,
                                               int* __restrict__ excl,
                                               int* __restrict__ bsum) {
    __shared__ int sd[256];
    int t = threadIdx.x, i = blockIdx.x * 256 + t;
    int v = 0;
    if (i < n) {
        int part = i / PART, off = i - part * PART;
#pragma unroll
        for (int r = 0; r < 8; ++r) v += histg[(size_t)(part * 8 + r) * PART + off];
    }
    sd[t] = v;
    __syncthreads();
    for (int off = 1; off < 256; off <<= 1) {
        int u = (t >= off) ? sd[t - off] : 0;
        __syncthreads();
        sd[t] += u;
        __syncthreads();
    }
    if (i < n) excl[i] = sd[t] - v;
    if (t == 255) bsum[blockIdx.x] = sd[255];
}

// ---- row_ptr + histg -> rbase (in place) ----
__global__ __launch_bounds__(256) void k_scan3b(int* __restrict__ histg,
                                                const int* __restrict__ excl,
                                                const int* __restrict__ bsum,
                                                int nbs, int n, int PART,
                                                int* __restrict__ row_ptr) {
    __shared__ int sd[256];
    int t = threadIdx.x;
    int v = (t < nbs) ? bsum[t] : 0;
    sd[t] = v;
    __syncthreads();
    for (int off = 1; off < 256; off <<= 1) {
        int u = (t >= off) ? sd[t - off] : 0;
        __syncthreads();
        sd[t] += u;
        __syncthreads();
    }
    int pref = (blockIdx.x == 0) ? 0 : sd[blockIdx.x - 1];
    int i = blockIdx.x * 256 + t;
    if (i < n) {
        int rp = pref + excl[i];
        row_ptr[i] = rp;
        int part = i / PART, off = i - part * PART;
        int run = rp;
#pragma unroll
        for (int r = 0; r < 8; ++r) {
            size_t idx = (size_t)(part * 8 + r) * PART + off;
            int h = histg[idx];
            histg[idx] = run;   // rbase
            run += h;
        }
        if (i == n - 1) row_ptr[n] = run;
    }
}

// ---- pass 3: placement via block-private LDS cursors (no global atomics) ----
__global__ __launch_bounds__(256) void k_place(const int4* __restrict__ tmp,
                                               const int* __restrict__ bstart,
                                               const int* __restrict__ bcnt,
                                               const int* __restrict__ rbase,
                                               int nchunk, int crange, int PART, int n,
                                               int2* __restrict__ csr0,
                                               int2* __restrict__ csr1) {
    __shared__ int cur[PARTMAX];
    int part = blockIdx.x & 31, r = blockIdx.x >> 5;
    for (int j = threadIdx.x; j < PART; j += 256)
        cur[j] = rbase[(size_t)(part * 8 + r) * PART + j];
    __syncthreads();
    int c0 = r * crange, c1 = min(c0 + crange, nchunk);
    int lo = part * PART;
    for (int c = c0; c < c1; ++c) {
        int s = bstart[c * NPARTS + part];
        int cnt = bcnt[c * NPARTS + part];
        for (int i = threadIdx.x; i < cnt; i += 256) {
            int4 rec = tmp[(size_t)s + i];
            int pos = atomicAdd(&cur[rec.w - lo], 1);
            csr0[pos] = make_int2(rec.x, rec.y);
            csr1[pos] = make_int2(rec.x, rec.z);
        }
    }
}

// ---- aggregation: one wave per node, 16-deep gather unroll ----
__global__ __launch_bounds__(512) void k_aggr(const uint* __restrict__ rep32,
                                              const int* __restrict__ row_ptr,
                                              const int2* __restrict__ csr,
                                              uint* __restrict__ xout, int n) {
    int wave = threadIdx.x >> 6, lane = threadIdx.x & 63;
    int node = blockIdx.x * 8 + wave;
    if (node >= n) return;
    int s0 = row_ptr[node], s1 = row_ptr[node + 1];
    float accx = 0.f, accy = 0.f, ssum = 0.f, amax = 0.f;
    int s = s0;
    for (; s + 16 <= s1; s += 16) {
        int2 cc[16];
        uint rr[16];
#pragma unroll
        for (int k = 0; k < 16; ++k) cc[k] = csr[s + k];
#pragma unroll
        for (int k = 0; k < 16; ++k) rr[k] = rep32[(size_t)cc[k].x * 64 + lane];
#pragma unroll
        for (int k = 0; k < 16; ++k) {
            float a = __int_as_float(cc[k].y);
            ssum += a;
            amax = fmaxf(amax, a);
            accx = fmaf(a, bf2f(rr[k] & 0xffffu), accx);
            accy = fmaf(a, bf2f(rr[k] >> 16), accy);
        }
    }
    for (; s + 4 <= s1; s += 4) {
        int2 cc[4];
        uint rr[4];
#pragma unroll
        for (int k = 0; k < 4; ++k) cc[k] = csr[s + k];
#pragma unroll
        for (int k = 0; k < 4; ++k) rr[k] = rep32[(size_t)cc[k].x * 64 + lane];
#pragma unroll
        for (int k = 0; k < 4; ++k) {
            float a = __int_as_float(cc[k].y);
            ssum += a;
            amax = fmaxf(amax, a);
            accx = fmaf(a, bf2f(rr[k] & 0xffffu), accx);
            accy = fmaf(a, bf2f(rr[k] >> 16), accy);
        }
    }
    for (; s < s1; ++s) {
        int2 c = csr[s];
        float a = __int_as_float(c.y);
        uint r = rep32[(size_t)c.x * 64 + lane];
        ssum += a;
        amax = fmaxf(amax, a);
        accx = fmaf(a, bf2f(r & 0xffffu), accx);
        accy = fmaf(a, bf2f(r >> 16), accy);
    }
    float inv = (s1 > s0) ? 1.f / (ssum + amax * 1e-16f) : 0.f;
    uint m = rep32[(size_t)node * 64 + lane];
    float ox = fmaf(accx, inv, bf2f(m & 0xffffu));
    float oy = fmaf(accy, inv, bf2f(m >> 16));
    xout[(size_t)node * 64 + lane] = f2bf(ox) | (f2bf(oy) << 16);
}

// ============================ dense MFMA kernels ============================
// 512 threads = 8 waves; wave handles 32 nodes (2 row-tiles of 16).
#define WROW 136  // shorts per LDS W row (128 + 8 pad -> 2-way banks = free)

// ---- MLP: rep(bf16) = LN(gelu(x(bf16) @ W^T + b)) ----
__global__ __launch_bounds__(512) void k_mlp(const uint* __restrict__ x32,
                                             const float* __restrict__ W,
                                             const float* __restrict__ b,
                                             const float* __restrict__ lw,
                                             const float* __restrict__ lb,
                                             uint* __restrict__ out32, int n) {
    __shared__ ushort Wbf[128 * WROW];
    uint* wd = (uint*)Wbf;
    for (int idx = threadIdx.x; idx < 128 * 64; idx += 512) {
        int row = idx >> 6, d = idx & 63;
        float2 w2 = *(const float2*)&W[row * 128 + d * 2];
        wd[row * (WROW / 2) + d] = f2bf(w2.x) | (f2bf(w2.y) << 16);
    }
    __syncthreads();
    int wv = threadIdx.x >> 6, l = threadIdx.x & 63;
    int c = l & 15, q = l >> 4;
    int base = blockIdx.x * 256 + wv * 32;
    int r0 = min(base + c, n - 1);
    int r1 = min(base + 16 + c, n - 1);

    f32x4 acc[2][8];
#pragma unroll
    for (int rt = 0; rt < 2; ++rt)
#pragma unroll
        for (int ct = 0; ct < 8; ++ct) acc[rt][ct] = (f32x4){0.f, 0.f, 0.f, 0.f};

#pragma unroll
    for (int kb = 0; kb < 4; ++kb) {
        ABu a0, a1;
        a0.u = *(const uint4*)&x32[(size_t)r0 * 64 + kb * 16 + q * 4];
        a1.u = *(const uint4*)&x32[(size_t)r1 * 64 + kb * 16 + q * 4];
#pragma unroll
        for (int ct = 0; ct < 8; ++ct) {
            bf16x8 bf = *(const bf16x8*)&Wbf[(ct * 16 + c) * WROW + kb * 32 + q * 8];
            acc[0][ct] = __builtin_amdgcn_mfma_f32_16x16x32_bf16(a0.v, bf, acc[0][ct], 0, 0, 0);
            acc[1][ct] = __builtin_amdgcn_mfma_f32_16x16x32_bf16(a1.v, bf, acc[1][ct], 0, 0, 0);
        }
    }

    float bias[8], lwv[8], lbv[8];
#pragma unroll
    for (int ct = 0; ct < 8; ++ct) {
        bias[ct] = b[ct * 16 + c];
        lwv[ct] = lw[ct * 16 + c];
        lbv[ct] = lb[ct * 16 + c];
    }

#pragma unroll
    for (int rt = 0; rt < 2; ++rt) {
#pragma unroll
        for (int ct = 0; ct < 8; ++ct)
#pragma unroll
            for (int i = 0; i < 4; ++i) {
                float h = acc[rt][ct][i] + bias[ct];
                acc[rt][ct][i] = 0.5f * h * (1.f + erff(h * 0.70710678118654752f));
            }
        float mu[4], rstd[4];
#pragma unroll
        for (int i = 0; i < 4; ++i) {
            float s = 0.f;
#pragma unroll
            for (int ct = 0; ct < 8; ++ct) s += acc[rt][ct][i];
            s += __shfl_xor(s, 1);
            s += __shfl_xor(s, 2);
            s += __shfl_xor(s, 4);
            s += __shfl_xor(s, 8);
            mu[i] = s * (1.f / 128.f);
        }
#pragma unroll
        for (int i = 0; i < 4; ++i) {
            float v = 0.f;
#pragma unroll
            for (int ct = 0; ct < 8; ++ct) {
                float d = acc[rt][ct][i] - mu[i];
                v += d * d;
            }
            v += __shfl_xor(v, 1);
            v += __shfl_xor(v, 2);
            v += __shfl_xor(v, 4);
            v += __shfl_xor(v, 8);
            rstd[i] = rsqrtf(v * (1.f / 128.f) + 1e-5f);
        }
#pragma unroll
        for (int ct = 0; ct < 8; ++ct)
#pragma unroll
            for (int i = 0; i < 4; ++i) {
                float o = (acc[rt][ct][i] - mu[i]) * rstd[i] * lwv[ct] + lbv[ct];
                float p = __shfl_xor(o, 1);
                uint dw = (c & 1) ? (f2bf(p) | (f2bf(o) << 16))
                                  : (f2bf(o) | (f2bf(p) << 16));
                int R = base + rt * 16 + q * 4 + i;
                if (R < n && (c & 1) == 0)
                    out32[(size_t)R * 64 + ct * 8 + (c >> 1)] = dw;
            }
    }
}

// ---- input projection: rep(bf16) = attr(f32) @ W^T + b ----
__global__ __launch_bounds__(512) void k_input(const float* __restrict__ attr,
                                               const float* __restrict__ W,
                                               const float* __restrict__ b,
                                               uint* __restrict__ out32, int n) {
    __shared__ ushort Wbf[128 * WROW];
    uint* wd = (uint*)Wbf;
    for (int idx = threadIdx.x; idx < 128 * 64; idx += 512) {
        int row = idx >> 6, d = idx & 63;
        float2 w2 = *(const float2*)&W[row * 128 + d * 2];
        wd[row * (WROW / 2) + d] = f2bf(w2.x) | (f2bf(w2.y) << 16);
    }
    __syncthreads();
    int wv = threadIdx.x >> 6, l = threadIdx.x & 63;
    int c = l & 15, q = l >> 4;
    int base = blockIdx.x * 256 + wv * 32;
    int r0 = min(base + c, n - 1);
    int r1 = min(base + 16 + c, n - 1);

    f32x4 acc[2][8];
#pragma unroll
    for (int rt = 0; rt < 2; ++rt)
#pragma unroll
        for (int ct = 0; ct < 8; ++ct) acc[rt][ct] = (f32x4){0.f, 0.f, 0.f, 0.f};

#pragma unroll
    for (int kb = 0; kb < 4; ++kb) {
        ABh a0, a1;
        float4 f0 = *(const float4*)&attr[(size_t)r0 * 128 + kb * 32 + q * 8];
        float4 f1 = *(const float4*)&attr[(size_t)r0 * 128 + kb * 32 + q * 8 + 4];
        a0.h[0] = f2bf(f0.x); a0.h[1] = f2bf(f0.y); a0.h[2] = f2bf(f0.z); a0.h[3] = f2bf(f0.w);
        a0.h[4] = f2bf(f1.x); a0.h[5] = f2bf(f1.y); a0.h[6] = f2bf(f1.z); a0.h[7] = f2bf(f1.w);
        float4 g0 = *(const float4*)&attr[(size_t)r1 * 128 + kb * 32 + q * 8];
        float4 g1 = *(const float4*)&attr[(size_t)r1 * 128 + kb * 32 + q * 8 + 4];
        a1.h[0] = f2bf(g0.x); a1.h[1] = f2bf(g0.y); a1.h[2] = f2bf(g0.z); a1.h[3] = f2bf(g0.w);
        a1.h[4] = f2bf(g1.x); a1.h[5] = f2bf(g1.y); a1.h[6] = f2bf(g1.z); a1.h[7] = f2bf(g1.w);
#pragma unroll
        for (int ct = 0; ct < 8; ++ct) {
            bf16x8 bf = *(const bf16x8*)&Wbf[(ct * 16 + c) * WROW + kb * 32 + q * 8];
            acc[0][ct] = __builtin_amdgcn_mfma_f32_16x16x32_bf16(a0.v, bf, acc[0][ct], 0, 0, 0);
            acc[1][ct] = __builtin_amdgcn_mfma_f32_16x16x32_bf16(a1.v, bf, acc[1][ct], 0, 0, 0);
        }
    }
    float bias[8];
#pragma unroll
    for (int ct = 0; ct < 8; ++ct) bias[ct] = b[ct * 16 + c];
#pragma unroll
    for (int rt = 0; rt < 2; ++rt)
#pragma unroll
        for (int ct = 0; ct < 8; ++ct)
#pragma unroll
            for (int i = 0; i < 4; ++i) {
                float o = acc[rt][ct][i] + bias[ct];
                float p = __shfl_xor(o, 1);
                uint dw = (c & 1) ? (f2bf(p) | (f2bf(o) << 16))
                                  : (f2bf(o) | (f2bf(p) << 16));
                int R = base + rt * 16 + q * 4 + i;
                if (R < n && (c & 1) == 0)
                    out32[(size_t)R * 64 + ct * 8 + (c >> 1)] = dw;
            }
}

// ---- output projection: out(f32) = rep(bf16) @ W_out^T + b_out (64 outs) ----
__global__ __launch_bounds__(512) void k_out(const uint* __restrict__ rep32,
                                             const float* __restrict__ W,
                                             const float* __restrict__ b,
                                             float* __restrict__ out, int n) {
    __shared__ ushort Wbf[64 * WROW];
    uint* wd = (uint*)Wbf;
    for (int idx = threadIdx.x; idx < 64 * 64; idx += 512) {
        int row = idx >> 6, d = idx & 63;
        float2 w2 = *(const float2*)&W[row * 128 + d * 2];
        wd[row * (WROW / 2) + d] = f2bf(w2.x) | (f2bf(w2.y) << 16);
    }
    __syncthreads();
    int wv = threadIdx.x >> 6, l = threadIdx.x & 63;
    int c = l & 15, q = l >> 4;
    int base = blockIdx.x * 256 + wv * 32;
    int r0 = min(base + c, n - 1);
    int r1 = min(base + 16 + c, n - 1);

    f32x4 acc[2][4];
#pragma unroll
    for (int rt = 0; rt < 2; ++rt)
#pragma unroll
        for (int ct = 0; ct < 4; ++ct) acc[rt][ct] = (f32x4){0.f, 0.f, 0.f, 0.f};

#pragma unroll
    for (int kb = 0; kb < 4; ++kb) {
        ABu a0, a1;
        a0.u = *(const uint4*)&rep32[(size_t)r0 * 64 + kb * 16 + q * 4];
        a1.u = *(const uint4*)&rep32[(size_t)r1 * 64 + kb * 16 + q * 4];
#pragma unroll
        for (int ct = 0; ct < 4; ++ct) {
            bf16x8 bf = *(const bf16x8*)&Wbf[(ct * 16 + c) * WROW + kb * 32 + q * 8];
            acc[0][ct] = __builtin_amdgcn_mfma_f32_16x16x32_bf16(a0.v, bf, acc[0][ct], 0, 0, 0);
            acc[1][ct] = __builtin_amdgcn_mfma_f32_16x16x32_bf16(a1.v, bf, acc[1][ct], 0, 0, 0);
        }
    }
    float bias[4];
#pragma unroll
    for (int ct = 0; ct < 4; ++ct) bias[ct] = b[ct * 16 + c];
#pragma unroll
    for (int rt = 0; rt < 2; ++rt)
#pragma unroll
        for (int ct = 0; ct < 4; ++ct)
#pragma unroll
            for (int i = 0; i < 4; ++i) {
                int R = base + rt * 16 + q * 4 + i;
                if (R < n) out[(size_t)R * 64 + ct * 16 + c] = acc[rt][ct][i] + bias[ct];
            }
}

extern "C" void kernel_launch(void* const* d_in, const int* in_sizes, int n_in,
                              void* d_out, int out_size, void* d_ws, size_t ws_size,
                              hipStream_t stream) {
    const float* node_attr = (const float*)d_in[0];
    const int* ei = (const int*)d_in[1];
    // d_in[2] = batch_idx (unused)
    const float* adv = (const float*)d_in[3];
    const float* W_inp = (const float*)d_in[4];
    const float* b_inp = (const float*)d_in[5];
    const float* W_a = (const float*)d_in[6];
    const float* b_a = (const float*)d_in[7];
    const float* ln_w = (const float*)d_in[8];
    const float* ln_b = (const float*)d_in[9];
    const float* W_out = (const float*)d_in[10];
    const float* b_out = (const float*)d_in[11];

    const int n = in_sizes[0] / 128;
    const int E = in_sizes[1] / 2;
    const int nchunk = (E + CHUNKE - 1) / CHUNKE;
    const int PART = (n + NPARTS - 1) / NPARTS;  // <= PARTMAX for n <= 65536
    const int crange = (nchunk + 7) / 8;

    // workspace: csr0,csr1 (E int2 each) | tmp (E int4; A,B overlay after
    // k_place: 2*n*64*4B <= E*16B) | histg 32*8*PART | excl n | row_ptr n+1 |
    // bsum 256 | bstart,bcnt nchunk*NPARTS each
    int2* csr0 = (int2*)d_ws;
    int2* csr1 = csr0 + E;
    int4* tmp = (int4*)(csr1 + E);
    uint* A = (uint*)tmp;      // overlays tmp (dead after k_place)
    uint* B = A + (size_t)n * 64;
    int* histg = (int*)(tmp + E);                 // 32*8*PART
    int* excl = histg + (size_t)NPARTS * 8 * PART;
    int* row_ptr = excl + n;                      // n+1
    int* bsum = row_ptr + n + 1;                  // 256
    int* bstart = bsum + 256;                     // nchunk*NPARTS
    int* bcnt = bstart + (size_t)nchunk * NPARTS;

    const int* src = ei;
    const int* dst = ei + E;

    int nbs = (n + 255) / 256;  // n <= 65536
    k_bin<<<nchunk, 512, 0, stream>>>(src, dst, adv, E, PART, tmp, bstart, bcnt);
    k_deg<<<256, 256, 0, stream>>>(tmp, bstart, bcnt, nchunk, crange, PART, n, histg);
    k_scan1<<<nbs, 256, 0, stream>>>(histg, PART, n, excl, bsum);
    k_scan3b<<<nbs, 256, 0, stream>>>(histg, excl, bsum, nbs, n, PART, row_ptr);
    k_place<<<256, 256, 0, stream>>>(tmp, bstart, bcnt, histg, nchunk, crange,
                                     PART, n, csr0, csr1);

    int nbd = (n + 255) / 256;  // dense kernels: 256 nodes/block
    int nb8 = (n + 7) / 8;
    k_input<<<nbd, 512, 0, stream>>>(node_attr, W_inp, b_inp, A, n);

    // layer 0: B = aggr(A); A = mlp(B)
    k_aggr<<<nb8, 512, 0, stream>>>(A, row_ptr, csr0, B, n);
    k_mlp<<<nbd, 512, 0, stream>>>(B, W_a, b_a, ln_w, ln_b, A, n);
    // layer 1: B = aggr(A); A = mlp(B)
    k_aggr<<<nb8, 512, 0, stream>>>(A, row_ptr, csr1, B, n);
    k_mlp<<<nbd, 512, 0, stream>>>(B, W_a + 128 * 128, b_a + 128,
                                   ln_w + 128, ln_b + 128, A, n);

    k_out<<<nbd, 512, 0, stream>>>(A, W_out, b_out, (float*)d_out, n);
}